// Round 9
// baseline (468.641 us; speedup 1.0000x reference)
//
#include <hip/hip_runtime.h>

typedef unsigned short u16;
typedef unsigned int   u32;

#define N_ 2
#define CH_ 64
#define H_ 156
#define W_ 156
#define L_ (H_*W_)          // 24336
#define C_ 16
#define CS_ 144
#define NH_ 4
#define K_ (L_/CS_)         // 169
#define HB_ 128
#define M_ (NH_*L_)         // 97344
#define NBINS 512
#define SORT_BLK 1024
#define NBLK ((M_+SORT_BLK-1)/SORT_BLK)   // 96
#define TS 16
#define NTX ((W_+TS-1)/TS)  // 10
#define NTY ((H_+TS-1)/TS)  // 10
#define CB_ 70              // LDS channel stride (bf16) -> <=2-way bank alias
#define RSTR_ (18*CB_)      // 1260

__device__ __forceinline__ u16 f2bf(float f) {
  union { float f; u32 u; } v; v.f = f;
  u32 r = (v.u + 0x7fffu + ((v.u >> 16) & 1u)) >> 16;   // RNE
  return (u16)r;
}
__device__ __forceinline__ float bf2f(u16 u) {
  union { u32 u; float f; } v; v.u = ((u32)u) << 16;
  return v.f;
}

typedef __attribute__((ext_vector_type(4))) short short4b;
typedef __attribute__((ext_vector_type(8))) short short8b;
typedef __attribute__((ext_vector_type(4))) float floatx4;

__device__ __forceinline__ short8b pack8(short4b lo, short4b hi) {
  short8b r;
  r[0]=lo[0]; r[1]=lo[1]; r[2]=lo[2]; r[3]=lo[3];
  r[4]=hi[0]; r[5]=hi[1]; r[6]=hi[2]; r[7]=hi[3];
  return r;
}

__device__ __forceinline__ floatx4 mfma32(short8b a, short8b b, floatx4 c) {
  return __builtin_amdgcn_mfma_f32_16x16x32_bf16(a, b, c, 0, 0, 0);
}

// ---------------- xe conv (f32, 16 ch) — 4x16 tiles, scalar-cached weights ---
__global__ __launch_bounds__(256) void conv_xe_kernel(
    const float* __restrict__ x, const float* __restrict__ wm,
    float* __restrict__ xe)
{
  __shared__ float xs[4][6][18];
  int ct = blockIdx.x % 10, rt = blockIdx.x / 10;
  int b = blockIdx.y;
  int x0 = ct*16, y0 = rt*4;
  int tid = threadIdx.x;
  int px = tid & 63;
  int col = px & 15, row = px >> 4;
  int og = __builtin_amdgcn_readfirstlane(tid >> 6);   // wave-uniform -> s_load weights
  const float* xb = x + (size_t)b*CH_*L_;
  const float* wg = wm + (size_t)og*4*CH_*9;

  float acc[4] = {0.f, 0.f, 0.f, 0.f};
  for (int c0 = 0; c0 < CH_; c0 += 4) {
    __syncthreads();
    for (int i = tid; i < 4*6*18; i += 256) {
      int cc = i / 108, r = i - cc*108;
      int ly = r / 18, lx = r - ly*18;
      int gy = y0 + ly - 1, gx = x0 + lx - 1;
      float v = (gy>=0 && gy<H_ && gx>=0 && gx<W_) ? xb[(size_t)(c0+cc)*L_ + (size_t)gy*W_ + gx] : 0.f;
      xs[cc][ly][lx] = v;
    }
    __syncthreads();
    #pragma unroll
    for (int cc = 0; cc < 4; ++cc) {
      float in[9];
      #pragma unroll
      for (int ky = 0; ky < 3; ++ky)
        #pragma unroll
        for (int kx = 0; kx < 3; ++kx)
          in[ky*3+kx] = xs[cc][row+ky][col+kx];
      const float* wc = wg + (size_t)(c0+cc)*9;
      #pragma unroll
      for (int oo = 0; oo < 4; ++oo) {
        const float* wo = wc + (size_t)oo*CH_*9;
        #pragma unroll
        for (int t = 0; t < 9; ++t) acc[oo] += in[t]*wo[t];
      }
    }
  }
  int gx = x0 + col, gy = y0 + row;
  if (gx < W_) {
    int p = gy*W_ + gx;
    *(float4*)(xe + ((size_t)b*L_+p)*C_ + og*4) = make_float4(acc[0],acc[1],acc[2],acc[3]);
  }
}

// ---------------- ye/fe conv via MFMA (implicit GEMM, bf16) ------------------
__global__ __launch_bounds__(256) void conv_mfma_kernel(
    const float* __restrict__ x, const u16* __restrict__ wpk,
    u16* __restrict__ yeb, u16* __restrict__ feb)
{
  __shared__ u16 xs[6*RSTR_];   // 15120 B
  int ct = blockIdx.x % 10, rt = blockIdx.x / 10;
  int b = blockIdx.y;
  int x0 = ct*16, y0 = rt*4;
  int tid = threadIdx.x;
  const float* xb = x + (size_t)b*CH_*L_;

  for (int idx = tid; idx < 64*108; idx += 256) {
    int c = idx / 108, rc = idx - c*108;
    int row = rc / 18, col = rc - row*18;
    int gy = y0 + row - 1, gx = x0 + col - 1;
    float v = (gy>=0 && gy<H_ && gx>=0 && gx<W_) ? xb[(size_t)c*L_ + (size_t)gy*W_ + gx] : 0.f;
    xs[row*RSTR_ + col*CB_ + c] = f2bf(v);
  }
  __syncthreads();

  int wave = tid >> 6, lane = tid & 63;
  int lg = lane >> 4, li = lane & 15;

  floatx4 acc[2][4];
  #pragma unroll
  for (int j = 0; j < 2; ++j)
    #pragma unroll
    for (int pr = 0; pr < 4; ++pr) acc[j][pr] = (floatx4)(0.f);

  #pragma unroll
  for (int tap = 0; tap < 9; ++tap) {
    int ky = tap / 3, kx = tap - ky*3;
    short8b A[2][2];
    #pragma unroll
    for (int j = 0; j < 2; ++j) {
      int ot = wave + j*4;
      const u16* wr = wpk + (((size_t)ot*9 + tap)*16 + li)*64;
      A[j][0] = pack8(*(const short4b*)(wr + lg*4),      *(const short4b*)(wr + 16 + lg*4));
      A[j][1] = pack8(*(const short4b*)(wr + 32 + lg*4), *(const short4b*)(wr + 48 + lg*4));
    }
    #pragma unroll
    for (int pr = 0; pr < 4; ++pr) {
      const u16* bp = xs + (pr+ky)*RSTR_ + (li+kx)*CB_;
      short8b B0 = pack8(*(const short4b*)(bp + lg*4),      *(const short4b*)(bp + 16 + lg*4));
      short8b B1 = pack8(*(const short4b*)(bp + 32 + lg*4), *(const short4b*)(bp + 48 + lg*4));
      acc[0][pr] = mfma32(A[0][0], B0, acc[0][pr]);
      acc[0][pr] = mfma32(A[0][1], B1, acc[0][pr]);
      acc[1][pr] = mfma32(A[1][0], B0, acc[1][pr]);
      acc[1][pr] = mfma32(A[1][1], B1, acc[1][pr]);
    }
  }

  int px = x0 + li;
  if (px < W_) {
    #pragma unroll
    for (int pr = 0; pr < 4; ++pr) {
      int p = (y0+pr)*W_ + px;
      short4b v0, v1;
      #pragma unroll
      for (int r = 0; r < 4; ++r) {
        v0[r] = (short)f2bf(acc[0][pr][r]);
        v1[r] = (short)f2bf(acc[1][pr][r]);
      }
      *(short4b*)(yeb + ((size_t)b*L_+p)*64 + wave*16 + lg*4) = v0;
      *(short4b*)(feb + ((size_t)b*L_+p)*64 + wave*16 + lg*4) = v1;
    }
  }
}

// ---------------- hashing: rot staged in LDS (broadcast reads) ---------------
__global__ __launch_bounds__(256) void hash_kernel(
    const float* __restrict__ xe, const float* __restrict__ rot,
    u16* __restrict__ xnb, int* __restrict__ codes)
{
  __shared__ float rl[NH_*HB_*C_];   // [h][i][f], 32 KB
  int tid = threadIdx.x;
  int b = blockIdx.y;
  for (int idx = tid; idx < NH_*HB_*C_; idx += 256) {
    int f = idx & 15; int hi = idx >> 4; int h = hi >> 7; int i = hi & 127;
    rl[idx] = rot[((size_t)f*NH_ + h)*HB_ + i];
  }
  __syncthreads();
  int t = blockIdx.x * 256 + tid;
  if (t >= L_) return;
  float xr[C_];
  float ss = 0.f;
  #pragma unroll
  for (int f = 0; f < C_; ++f) { xr[f] = xe[((size_t)b*L_ + t)*C_ + f]; ss += xr[f]*xr[f]; }
  float inv = 1.f / fmaxf(sqrtf(ss), 5e-5f);
  u32 w[8];
  #pragma unroll
  for (int q = 0; q < 8; ++q)
    w[q] = (u32)f2bf(xr[2*q]*inv) | ((u32)f2bf(xr[2*q+1]*inv) << 16);
  uint4* d = (uint4*)(xnb + ((size_t)b*L_ + t)*C_);
  d[0] = make_uint4(w[0],w[1],w[2],w[3]);
  d[1] = make_uint4(w[4],w[5],w[6],w[7]);
  #pragma unroll
  for (int h = 0; h < NH_; ++h) {
    float best = -1e30f; int bi = 0;
    #pragma unroll 2
    for (int i = 0; i < HB_; ++i) {
      const float4* rp = (const float4*)(rl + (h*HB_ + i)*C_);
      float4 r0 = rp[0], r1 = rp[1], r2 = rp[2], r3 = rp[3];
      float v = 0.f;
      v += xr[0]*r0.x;  v += xr[1]*r0.y;  v += xr[2]*r0.z;  v += xr[3]*r0.w;
      v += xr[4]*r1.x;  v += xr[5]*r1.y;  v += xr[6]*r1.z;  v += xr[7]*r1.w;
      v += xr[8]*r2.x;  v += xr[9]*r2.y;  v += xr[10]*r2.z; v += xr[11]*r2.w;
      v += xr[12]*r3.x; v += xr[13]*r3.y; v += xr[14]*r3.z; v += xr[15]*r3.w;
      if (v > best) { best = v; bi = i; }
    }
    codes[(size_t)b*M_ + h*L_ + t] = bi + h*HB_;
  }
}

// ---------------- weight prep: fc weights bf16 + conv weights A-frag pack ----
__global__ __launch_bounds__(256) void prep_w_kernel(
    const float* __restrict__ w1, const float* __restrict__ w2,
    const float* __restrict__ wa, const float* __restrict__ wf,
    u16* __restrict__ w1b, u16* __restrict__ w2b, u16* __restrict__ wpk)
{
  int i = blockIdx.x*256 + threadIdx.x;
  if (i < CS_*CH_)  w1b[i] = f2bf(w1[i]);
  if (i < CS_*CS_)  w2b[i] = f2bf(w2[i]);
  if (i < 8*9*16*64) {
    int ot = i / (9*16*64); int r = i - ot*(9*16*64);
    int tap = r / (16*64);  int r2 = r - tap*(16*64);
    int o = r2 >> 6, c = r2 & 63;
    const float* src = (ot < 4) ? wa : wf;
    int og = (ot & 3)*16 + o;
    wpk[i] = f2bf(src[((size_t)og*64 + c)*9 + tap]);
  }
}

// ---------------- per-pixel FC via MFMA ------------------------------------
__global__ __launch_bounds__(256) void fc_mfma_kernel(
    const u16* __restrict__ feb, const u16* __restrict__ w1b, const float* __restrict__ b1,
    const u16* __restrict__ w2b, const float* __restrict__ b2, u16* __restrict__ fc2b)
{
  int wid = blockIdx.x*4 + (threadIdx.x >> 6);
  if (wid >= 2*(L_/16)) return;
  int b = wid / (L_/16);
  int p0 = (wid - b*(L_/16)) * 16;
  int lane = threadIdx.x & 63;
  int lg = lane >> 4, li = lane & 15;

  const u16* fr = feb + ((size_t)b*L_ + p0 + li)*CH_;
  short8b feB[2];
  #pragma unroll
  for (int ks = 0; ks < 2; ++ks)
    feB[ks] = pack8(*(const short4b*)(fr + ks*32 + lg*4),
                    *(const short4b*)(fr + ks*32 + 16 + lg*4));

  short4b hq[9];
  #pragma unroll
  for (int s = 0; s < 9; ++s) {
    const u16* wr = w1b + (size_t)(s*16 + li)*CH_ + lg*4;
    short8b a0 = pack8(*(const short4b*)(wr),      *(const short4b*)(wr + 16));
    short8b a1 = pack8(*(const short4b*)(wr + 32), *(const short4b*)(wr + 48));
    floatx4 acc = mfma32(a0, feB[0], (floatx4)(0.f));
    acc = mfma32(a1, feB[1], acc);
    float4 bb = *(const float4*)(b1 + s*16 + lg*4);
    short4b hv;
    hv[0] = (short)f2bf(fmaxf(acc[0] + bb.x, 0.f));
    hv[1] = (short)f2bf(fmaxf(acc[1] + bb.y, 0.f));
    hv[2] = (short)f2bf(fmaxf(acc[2] + bb.z, 0.f));
    hv[3] = (short)f2bf(fmaxf(acc[3] + bb.w, 0.f));
    hq[s] = hv;
  }
  short4b zero4; zero4[0]=0; zero4[1]=0; zero4[2]=0; zero4[3]=0;
  short8b hB[5];
  #pragma unroll
  for (int ks = 0; ks < 4; ++ks) hB[ks] = pack8(hq[2*ks], hq[2*ks+1]);
  hB[4] = pack8(hq[8], zero4);

  u16* orow = fc2b + ((size_t)b*L_ + p0 + li)*CS_;
  #pragma unroll
  for (int s2 = 0; s2 < 9; ++s2) {
    const u16* wr = w2b + (size_t)(s2*16 + li)*CS_;
    floatx4 acc = (floatx4)(0.f);
    #pragma unroll
    for (int ks = 0; ks < 5; ++ks) {
      short4b lo = *(const short4b*)(wr + ks*32 + lg*4);
      short4b hi = (ks < 4) ? *(const short4b*)(wr + ks*32 + 16 + lg*4) : zero4;
      acc = mfma32(pack8(lo, hi), hB[ks], acc);
    }
    float4 bb = *(const float4*)(b2 + s2*16 + lg*4);
    short4b ov;
    ov[0] = (short)f2bf(acc[0] + bb.x);
    ov[1] = (short)f2bf(acc[1] + bb.y);
    ov[2] = (short)f2bf(acc[2] + bb.z);
    ov[3] = (short)f2bf(acc[3] + bb.w);
    *(short4b*)(orow + s2*16 + lg*4) = ov;
  }
}

// ---------------- stable counting sort: histogram ----------------------------
__global__ __launch_bounds__(256) void hist_kernel(
    const int* __restrict__ codes, int* __restrict__ hist)
{
  __shared__ int lh[NBINS];
  int eb = blockIdx.x, b = blockIdx.y;
  for (int i = threadIdx.x; i < NBINS; i += 256) lh[i] = 0;
  __syncthreads();
  int base = eb * SORT_BLK;
  int end = min(base + SORT_BLK, M_);
  for (int i = base + threadIdx.x; i < end; i += 256)
    atomicAdd(&lh[codes[(size_t)b*M_ + i]], 1);
  __syncthreads();
  for (int i = threadIdx.x; i < NBINS; i += 256)
    hist[((size_t)b*NBLK + eb)*NBINS + i] = lh[i];
}

// ---------------- counting sort: per-bin cross-block prefix ------------------
__global__ __launch_bounds__(NBINS) void prefix_kernel(
    const int* __restrict__ hist, int* __restrict__ blockoff, int* __restrict__ bin_start)
{
  int b = blockIdx.x;
  int c = threadIdx.x;
  int run = 0;
  for (int eb = 0; eb < NBLK; ++eb) {
    size_t idx = ((size_t)b*NBLK + eb)*NBINS + c;
    int v = hist[idx];
    blockoff[idx] = run;
    run += v;
  }
  __shared__ int tot[NBINS];
  tot[c] = run;
  __syncthreads();
  if (c == 0) {
    int s = 0;
    for (int i = 0; i < NBINS; ++i) { int v = tot[i]; tot[i] = s; s += v; }
  }
  __syncthreads();
  bin_start[b*NBINS + c] = tot[c];
}

// ---------------- counting sort: stable in-order scatter ---------------------
__global__ __launch_bounds__(64) void scatter_kernel(
    const int* __restrict__ codes, const int* __restrict__ bin_start,
    const int* __restrict__ blockoff, int* __restrict__ idx_sorted)
{
  __shared__ int off[NBINS];
  __shared__ int lc[SORT_BLK];
  int eb = blockIdx.x, b = blockIdx.y;
  for (int i = threadIdx.x; i < NBINS; i += 64)
    off[i] = bin_start[b*NBINS + i] + blockoff[((size_t)b*NBLK + eb)*NBINS + i];
  int base = eb * SORT_BLK;
  int end = min(base + SORT_BLK, M_);
  for (int i = base + threadIdx.x; i < end; i += 64)
    lc[i - base] = codes[(size_t)b*M_ + i];
  __syncthreads();
  if (threadIdx.x == 0) {
    int n = end - base;
    for (int i = 0; i < n; ++i) {
      int c = lc[i];
      int p = off[c]++;
      idx_sorted[(size_t)b*M_ + p] = base + i;
    }
  }
}

// ---------------- bucket attention: MFMA flash-style, 3 waves ----------------
// LDS 45KB (V chunked 224+208) -> 3 blocks/CU; retbuf bf16; setprio on PV.
__global__ __launch_bounds__(192) void bucket_kernel(
    const float* __restrict__ xe, const u16* __restrict__ xnb,
    const u16* __restrict__ yeb, const u16* __restrict__ fc2b,
    const int* __restrict__ idx_sorted,
    u16* __restrict__ retbuf, float* __restrict__ bsbuf)
{
  __shared__ char smem[45056];
  u16* k_lds = (u16*)smem;                 // [432][16]       13824 B
  u16* v_lds = (u16*)(smem + 13824);       // [64][226] chunk 28928 B
  int* tj    = (int*)(smem + 42752);       // [432]            1728 B
  int* o_own = (int*)(smem + 44480);       // [144]             576 B
  u16* o_lds = (u16*)smem;                 // [144][72] (aliases k/v after use)

  int flat = blockIdx.x;
  int sid = (flat & 7)*169 + (flat >> 3);
  int k  = sid % K_;
  int hb = sid / K_;
  int h = hb & 3, b = hb >> 2;
  int tid = threadIdx.x;
  int kprev = (k + K_ - 1) % K_, knext = (k + 1) % K_;
  const int* iss = idx_sorted + (size_t)b*M_ + (size_t)h*K_*CS_;
  const u16* xnbb = xnb + (size_t)b*L_*C_;

  for (int j = tid; j < 3*CS_; j += 192) {
    int jb = j / CS_, ji = j - jb*CS_;
    int kj = jb==0 ? k : (jb==1 ? kprev : knext);
    int orig = iss[kj*CS_ + ji];
    int t = orig % L_;
    tj[j] = t;
    if (jb == 0) o_own[ji] = orig;
    const uint4* s = (const uint4*)(xnbb + (size_t)t*C_);
    uint4* d = (uint4*)(k_lds + j*16);
    d[0] = s[0]; d[1] = s[1];
  }
  __syncthreads();    // tj ready (V staging reads it)

  // stage V^T chunk A: keys 0..223 (112 pairs), [ch][226] layout
  const u16* yb = yeb + (size_t)b*L_*64;
  for (int idx = tid; idx < 112*64; idx += 192) {
    int p2 = idx >> 6, ch = idx & 63;
    u32 lo = yb[(size_t)tj[2*p2]*64 + ch];
    u32 hi = yb[(size_t)tj[2*p2+1]*64 + ch];
    ((u32*)v_lds)[ch*113 + p2] = lo | (hi << 16);
  }

  int wave = tid >> 6, lane = tid & 63;
  int lg = lane >> 4, li = lane & 15;
  int wq0 = wave * 48;

  short4b zero4; zero4[0]=0; zero4[1]=0; zero4[2]=0; zero4[3]=0;

  short8b qb[3];
  const float* xeb_ = xe + (size_t)b*L_*C_;
  #pragma unroll
  for (int n = 0; n < 3; ++n) {
    int t = tj[wq0 + n*16 + li];
    const float* q = xeb_ + (size_t)t*C_ + lg*4;
    short4b v;
    v[0] = (short)f2bf(q[0]); v[1] = (short)f2bf(q[1]);
    v[2] = (short)f2bf(q[2]); v[3] = (short)f2bf(q[3]);
    qb[n] = pack8(v, zero4);
  }

  const u16* fb = fc2b + (size_t)b*L_*CS_;
  u16 bnx[2][3][4];
  #pragma unroll
  for (int s2 = 0; s2 < 2; ++s2)
    #pragma unroll
    for (int r = 0; r < 4; ++r) {
      int t = tj[s2*16 + lg*4 + r];
      #pragma unroll
      for (int n = 0; n < 3; ++n)
        bnx[s2][n][r] = fb[(size_t)t*CS_ + wq0 + n*16 + li];
    }
  __syncthreads();    // V chunk A ready

  floatx4 oacc[4][3];
  #pragma unroll
  for (int cg = 0; cg < 4; ++cg)
    #pragma unroll
    for (int n = 0; n < 3; ++n)
      oacc[cg][n] = (floatx4)(0.f);
  float mrun[3] = {-1e30f,-1e30f,-1e30f};
  float lsum[3] = {0.f,0.f,0.f};

  for (int p = 0; p < 13; ++p) {
    if (p == 7) {
      __syncthreads();   // all waves done reading chunk A
      // stage V^T chunk B: keys 224..431 (104 pairs)
      for (int idx = tid; idx < 104*64; idx += 192) {
        int p2 = idx >> 6, ch = idx & 63;
        int kk = 224 + 2*p2;
        u32 lo = yb[(size_t)tj[kk]*64 + ch];
        u32 hi = yb[(size_t)tj[kk+1]*64 + ch];
        ((u32*)v_lds)[ch*113 + p2] = lo | (hi << 16);
      }
      __syncthreads();
    }
    int t0 = 2*p, t1 = 2*p+1;
    short8b ak0 = pack8(*(const short4b*)(k_lds + (size_t)(t0*16 + li)*16 + lg*4), zero4);
    short8b ak1 = pack8(*(const short4b*)(k_lds + (size_t)(t1*16 + li)*16 + lg*4), zero4);
    floatx4 s0[3], s1[3];
    #pragma unroll
    for (int n = 0; n < 3; ++n) {
      s0[n] = mfma32(ak0, qb[n], (floatx4)(0.f));
      s1[n] = mfma32(ak1, qb[n], (floatx4)(0.f));
    }
    float bias0[3][4], bias1[3][4];
    #pragma unroll
    for (int n = 0; n < 3; ++n)
      #pragma unroll
      for (int r = 0; r < 4; ++r) {
        bias0[n][r] = bf2f(bnx[0][n][r]);
        bias1[n][r] = bf2f(bnx[1][n][r]);
      }
    if (p < 12) {
      #pragma unroll
      for (int s2 = 0; s2 < 2; ++s2)
        #pragma unroll
        for (int r = 0; r < 4; ++r) {
          int t = tj[(2*p+2+s2)*16 + lg*4 + r];
          #pragma unroll
          for (int n = 0; n < 3; ++n)
            bnx[s2][n][r] = fb[(size_t)t*CS_ + wq0 + n*16 + li];
        }
    } else {
      #pragma unroll
      for (int r = 0; r < 4; ++r) {
        int t = tj[26*16 + lg*4 + r];
        #pragma unroll
        for (int n = 0; n < 3; ++n)
          bnx[0][n][r] = fb[(size_t)t*CS_ + wq0 + n*16 + li];
      }
    }

    short8b pb[3];
    #pragma unroll
    for (int n = 0; n < 3; ++n) {
      float a0[4], a1[4];
      #pragma unroll
      for (int r = 0; r < 4; ++r) { a0[r] = s0[n][r] + bias0[n][r]; a1[r] = s1[n][r] + bias1[n][r]; }
      float tmax = fmaxf(fmaxf(fmaxf(a0[0],a0[1]), fmaxf(a0[2],a0[3])),
                         fmaxf(fmaxf(a1[0],a1[1]), fmaxf(a1[2],a1[3])));
      tmax = fmaxf(tmax, __shfl_xor(tmax, 16));
      tmax = fmaxf(tmax, __shfl_xor(tmax, 32));
      if (__any(tmax > mrun[n] + 8.f)) {
        float mn = fmaxf(mrun[n], tmax);
        float sc = __expf(mrun[n] - mn);
        lsum[n] *= sc;
        #pragma unroll
        for (int cg = 0; cg < 4; ++cg) {
          oacc[cg][n][0] *= sc; oacc[cg][n][1] *= sc;
          oacc[cg][n][2] *= sc; oacc[cg][n][3] *= sc;
        }
        mrun[n] = mn;
      }
      float pv0[4], pv1[4];
      float ls = 0.f;
      #pragma unroll
      for (int r = 0; r < 4; ++r) {
        pv0[r] = __expf(a0[r] - mrun[n]);
        pv1[r] = __expf(a1[r] - mrun[n]);
        ls += pv0[r] + pv1[r];
      }
      lsum[n] += ls;
      short4b plo, phi;
      #pragma unroll
      for (int r = 0; r < 4; ++r) {
        plo[r] = (short)f2bf(pv0[r]);
        phi[r] = (short)f2bf(pv1[r]);
      }
      pb[n] = pack8(plo, phi);
    }
    int vloc = (p < 7) ? p*32 : (p-7)*32;
    __builtin_amdgcn_s_setprio(1);
    #pragma unroll
    for (int cg = 0; cg < 4; ++cg) {
      const u16* vr = v_lds + (size_t)(cg*16 + li)*226 + vloc + lg*4;
      short8b av = pack8(*(const short4b*)vr, *(const short4b*)(vr + 16));
      #pragma unroll
      for (int n = 0; n < 3; ++n)
        oacc[cg][n] = mfma32(av, pb[n], oacc[cg][n]);
    }
    __builtin_amdgcn_s_setprio(0);
  }

  // tail: tile 26 (keys 416..431 = local 192..207 of chunk B)
  {
    short8b ak0 = pack8(*(const short4b*)(k_lds + (size_t)(26*16 + li)*16 + lg*4), zero4);
    floatx4 s0[3];
    #pragma unroll
    for (int n = 0; n < 3; ++n)
      s0[n] = mfma32(ak0, qb[n], (floatx4)(0.f));
    short8b pb[3];
    #pragma unroll
    for (int n = 0; n < 3; ++n) {
      float a0[4];
      #pragma unroll
      for (int r = 0; r < 4; ++r) a0[r] = s0[n][r] + bf2f(bnx[0][n][r]);
      float tmax = fmaxf(fmaxf(a0[0],a0[1]), fmaxf(a0[2],a0[3]));
      tmax = fmaxf(tmax, __shfl_xor(tmax, 16));
      tmax = fmaxf(tmax, __shfl_xor(tmax, 32));
      if (__any(tmax > mrun[n] + 8.f)) {
        float mn = fmaxf(mrun[n], tmax);
        float sc = __expf(mrun[n] - mn);
        lsum[n] *= sc;
        #pragma unroll
        for (int cg = 0; cg < 4; ++cg) {
          oacc[cg][n][0] *= sc; oacc[cg][n][1] *= sc;
          oacc[cg][n][2] *= sc; oacc[cg][n][3] *= sc;
        }
        mrun[n] = mn;
      }
      float ls = 0.f;
      short4b plo;
      #pragma unroll
      for (int r = 0; r < 4; ++r) {
        float pv = __expf(a0[r] - mrun[n]);
        ls += pv;
        plo[r] = (short)f2bf(pv);
      }
      lsum[n] += ls;
      pb[n] = pack8(plo, zero4);
    }
    __builtin_amdgcn_s_setprio(1);
    #pragma unroll
    for (int cg = 0; cg < 4; ++cg) {
      const u16* vr = v_lds + (size_t)(cg*16 + li)*226 + 192 + lg*4;
      short8b av = pack8(*(const short4b*)vr, zero4);
      #pragma unroll
      for (int n = 0; n < 3; ++n)
        oacc[cg][n] = mfma32(av, pb[n], oacc[cg][n]);
    }
    __builtin_amdgcn_s_setprio(0);
  }

  float bs[3], inv[3];
  #pragma unroll
  for (int n = 0; n < 3; ++n) {
    float ls = lsum[n];
    ls += __shfl_xor(ls, 16);
    ls += __shfl_xor(ls, 32);
    inv[n] = 1.f / ls;
    bs[n] = mrun[n] + logf(ls);
  }
  if (lane < 16) {
    #pragma unroll
    for (int n = 0; n < 3; ++n)
      bsbuf[(size_t)b*M_ + o_own[wq0 + n*16 + lane]] = bs[n];
  }
  __syncthreads();    // all waves done with k_lds/v_lds -> reuse as o_lds (bf16)
  #pragma unroll
  for (int cg = 0; cg < 4; ++cg)
    #pragma unroll
    for (int n = 0; n < 3; ++n) {
      short4b ov;
      #pragma unroll
      for (int r = 0; r < 4; ++r) ov[r] = (short)f2bf(oacc[cg][n][r] * inv[n]);
      *(short4b*)(o_lds + (size_t)(wq0 + n*16 + li)*72 + cg*16 + lg*4) = ov;
    }
  __syncthreads();
  u16* rbb = retbuf + (size_t)b*M_*64;
  for (int rr = tid >> 4; rr < 144; rr += 12) {
    int c4 = (tid & 15)*4;
    short4b v = *(const short4b*)(o_lds + (size_t)rr*72 + c4);
    *(short4b*)(rbb + (size_t)o_own[rr]*64 + c4) = v;
  }
}

// ---------------- combine hash rounds (softmax over NH) + residual -----------
__global__ __launch_bounds__(256) void combine_kernel(
    const u16* __restrict__ retbuf, const float* __restrict__ bsbuf,
    const float* __restrict__ x, float* __restrict__ out)
{
  __shared__ float s[64][65];
  __shared__ float prob[NH_][64];
  int b = blockIdx.y;
  int p0 = blockIdx.x * 64;
  int tid = threadIdx.x;
  if (tid < 64) {
    int p = min(p0 + tid, L_-1);
    float bs0 = bsbuf[(size_t)b*M_ + 0*L_ + p];
    float bs1 = bsbuf[(size_t)b*M_ + 1*L_ + p];
    float bs2 = bsbuf[(size_t)b*M_ + 2*L_ + p];
    float bs3 = bsbuf[(size_t)b*M_ + 3*L_ + p];
    float mx = fmaxf(fmaxf(bs0,bs1), fmaxf(bs2,bs3));
    float e0 = __expf(bs0-mx), e1 = __expf(bs1-mx), e2 = __expf(bs2-mx), e3 = __expf(bs3-mx);
    float inv = 1.f / (e0+e1+e2+e3);
    prob[0][tid] = e0*inv; prob[1][tid] = e1*inv;
    prob[2][tid] = e2*inv; prob[3][tid] = e3*inv;
  }
  __syncthreads();
  for (int i = tid; i < 64*64; i += 256) {
    int pp = i >> 6, c = i & 63;
    int p = min(p0 + pp, L_-1);
    float v = 0.f;
    #pragma unroll
    for (int h = 0; h < NH_; ++h)
      v += bf2f(retbuf[(((size_t)b*NH_ + h)*L_ + p)*CH_ + c]) * prob[h][pp];
    s[c][pp] = v;
  }
  __syncthreads();
  for (int i = tid; i < 64*64; i += 256) {
    int pp = i & 63, cc = i >> 6;
    int p = p0 + pp;
    if (p < L_) {
      size_t gi = ((size_t)b*CH_ + cc)*L_ + p;
      out[gi] = s[cc][pp] + x[gi];
    }
  }
}

extern "C" void kernel_launch(void* const* d_in, const int* in_sizes, int n_in,
                              void* d_out, int out_size, void* d_ws, size_t ws_size,
                              hipStream_t stream) {
  const float* x   = (const float*)d_in[0];
  const float* wm  = (const float*)d_in[1];
  const float* wa  = (const float*)d_in[2];
  const float* wf  = (const float*)d_in[3];
  const float* fw1 = (const float*)d_in[4];
  const float* fb1 = (const float*)d_in[5];
  const float* fw2 = (const float*)d_in[6];
  const float* fb2 = (const float*)d_in[7];
  const float* rot = (const float*)d_in[8];
  float* out = (float*)d_out;

  char* p = (char*)d_ws;
  auto alloc = [&](size_t bytes) { char* r = p; p += (bytes + 255) & ~(size_t)255; return r; };
  float* xe      = (float*)alloc(sizeof(float)*(size_t)N_*L_*C_);
  u16*   xnb     = (u16*)  alloc(sizeof(u16)*(size_t)N_*L_*C_);
  u16*   yeb     = (u16*)  alloc(sizeof(u16)*(size_t)N_*L_*CH_);
  u16*   feb     = (u16*)  alloc(sizeof(u16)*(size_t)N_*L_*CH_);
  u16*   fc2b    = (u16*)  alloc(sizeof(u16)*(size_t)N_*L_*CS_);
  u16*   retbuf  = (u16*)  alloc(sizeof(u16)*(size_t)N_*M_*CH_);
  float* bsbuf   = (float*)alloc(sizeof(float)*(size_t)N_*M_);
  int* codes     = (int*)alloc(sizeof(int)*(size_t)N_*M_);
  int* idx_sorted= (int*)alloc(sizeof(int)*(size_t)N_*M_);
  int* hist      = (int*)alloc(sizeof(int)*(size_t)N_*NBLK*NBINS);
  int* blockoff  = (int*)alloc(sizeof(int)*(size_t)N_*NBLK*NBINS);
  int* bin_start = (int*)alloc(sizeof(int)*(size_t)N_*NBINS);
  u16* w1b       = (u16*)alloc(sizeof(u16)*(size_t)CS_*CH_);
  u16* w2b       = (u16*)alloc(sizeof(u16)*(size_t)CS_*CS_);
  u16* wpk       = (u16*)alloc(sizeof(u16)*(size_t)8*9*16*64);

  // 1a. weight prep (fc bf16 + conv A-frag pack)
  prep_w_kernel<<<dim3((8*9*16*64 + 255)/256), 256, 0, stream>>>(fw1, fw2, wa, wf, w1b, w2b, wpk);
  // 1b. xe conv (f32, scalar-cached weights)
  conv_xe_kernel<<<dim3(10*39, N_), 256, 0, stream>>>(x, wm, xe);
  // 1c. ye/fe conv (MFMA bf16)
  conv_mfma_kernel<<<dim3(10*39, N_), 256, 0, stream>>>(x, wpk, yeb, feb);
  // 2. hash + xnorm(bf16), rot in LDS
  hash_kernel<<<dim3((L_ + 255)/256, N_), 256, 0, stream>>>(xe, rot, xnb, codes);
  // 3. per-pixel FC via MFMA (bf16)
  {
    int tiles = 2*(L_/16);
    fc_mfma_kernel<<<dim3((tiles + 3)/4), 256, 0, stream>>>(feb, w1b, fb1, w2b, fb2, fc2b);
  }
  // 4. stable counting sort
  {
    dim3 g(NBLK, N_);
    hist_kernel<<<g, 256, 0, stream>>>(codes, hist);
    prefix_kernel<<<dim3(N_), NBINS, 0, stream>>>(hist, blockoff, bin_start);
    scatter_kernel<<<g, 64, 0, stream>>>(codes, bin_start, blockoff, idx_sorted);
  }
  // 5. bucket attention (MFMA, bf16 out)
  bucket_kernel<<<dim3(K_*NH_*N_), 192, 0, stream>>>(xe, xnb, yeb, fc2b,
                                                     idx_sorted, retbuf, bsbuf);
  // 6. combine
  combine_kernel<<<dim3((L_ + 63)/64, N_), 256, 0, stream>>>(retbuf, bsbuf, x, out);
}

// Round 10
// 422.754 us; speedup vs baseline: 1.1085x; 1.1085x over previous
//
#include <hip/hip_runtime.h>

typedef unsigned short u16;
typedef unsigned int   u32;

#define N_ 2
#define CH_ 64
#define H_ 156
#define W_ 156
#define L_ (H_*W_)          // 24336
#define C_ 16
#define CS_ 144
#define NH_ 4
#define K_ (L_/CS_)         // 169
#define HB_ 128
#define M_ (NH_*L_)         // 97344
#define NBINS 512
#define SORT_BLK 1024
#define NBLK ((M_+SORT_BLK-1)/SORT_BLK)   // 96
#define TS 16
#define NTX ((W_+TS-1)/TS)  // 10
#define NTY ((H_+TS-1)/TS)  // 10
#define CB_ 70              // LDS channel stride (bf16) -> <=2-way bank alias
#define RSTR_ (18*CB_)      // 1260

__device__ __forceinline__ u16 f2bf(float f) {
  union { float f; u32 u; } v; v.f = f;
  u32 r = (v.u + 0x7fffu + ((v.u >> 16) & 1u)) >> 16;   // RNE
  return (u16)r;
}
__device__ __forceinline__ float bf2f(u16 u) {
  union { u32 u; float f; } v; v.u = ((u32)u) << 16;
  return v.f;
}

typedef __attribute__((ext_vector_type(4))) short short4b;
typedef __attribute__((ext_vector_type(8))) short short8b;
typedef __attribute__((ext_vector_type(4))) float floatx4;

__device__ __forceinline__ short8b pack8(short4b lo, short4b hi) {
  short8b r;
  r[0]=lo[0]; r[1]=lo[1]; r[2]=lo[2]; r[3]=lo[3];
  r[4]=hi[0]; r[5]=hi[1]; r[6]=hi[2]; r[7]=hi[3];
  return r;
}

__device__ __forceinline__ floatx4 mfma32(short8b a, short8b b, floatx4 c) {
  return __builtin_amdgcn_mfma_f32_16x16x32_bf16(a, b, c, 0, 0, 0);
}

// ---------------- xe conv (f32, 16 ch) — 4x16 tiles, scalar-cached weights ---
__global__ __launch_bounds__(256) void conv_xe_kernel(
    const float* __restrict__ x, const float* __restrict__ wm,
    float* __restrict__ xe)
{
  __shared__ float xs[4][6][18];
  int ct = blockIdx.x % 10, rt = blockIdx.x / 10;
  int b = blockIdx.y;
  int x0 = ct*16, y0 = rt*4;
  int tid = threadIdx.x;
  int px = tid & 63;
  int col = px & 15, row = px >> 4;
  int og = __builtin_amdgcn_readfirstlane(tid >> 6);   // wave-uniform -> s_load weights
  const float* xb = x + (size_t)b*CH_*L_;
  const float* wg = wm + (size_t)og*4*CH_*9;

  float acc[4] = {0.f, 0.f, 0.f, 0.f};
  for (int c0 = 0; c0 < CH_; c0 += 4) {
    __syncthreads();
    for (int i = tid; i < 4*6*18; i += 256) {
      int cc = i / 108, r = i - cc*108;
      int ly = r / 18, lx = r - ly*18;
      int gy = y0 + ly - 1, gx = x0 + lx - 1;
      float v = (gy>=0 && gy<H_ && gx>=0 && gx<W_) ? xb[(size_t)(c0+cc)*L_ + (size_t)gy*W_ + gx] : 0.f;
      xs[cc][ly][lx] = v;
    }
    __syncthreads();
    #pragma unroll
    for (int cc = 0; cc < 4; ++cc) {
      float in[9];
      #pragma unroll
      for (int ky = 0; ky < 3; ++ky)
        #pragma unroll
        for (int kx = 0; kx < 3; ++kx)
          in[ky*3+kx] = xs[cc][row+ky][col+kx];
      const float* wc = wg + (size_t)(c0+cc)*9;
      #pragma unroll
      for (int oo = 0; oo < 4; ++oo) {
        const float* wo = wc + (size_t)oo*CH_*9;
        #pragma unroll
        for (int t = 0; t < 9; ++t) acc[oo] += in[t]*wo[t];
      }
    }
  }
  int gx = x0 + col, gy = y0 + row;
  if (gx < W_) {
    int p = gy*W_ + gx;
    *(float4*)(xe + ((size_t)b*L_+p)*C_ + og*4) = make_float4(acc[0],acc[1],acc[2],acc[3]);
  }
}

// ---------------- ye/fe conv via MFMA (implicit GEMM, bf16) ------------------
__global__ __launch_bounds__(256) void conv_mfma_kernel(
    const float* __restrict__ x, const u16* __restrict__ wpk,
    u16* __restrict__ yeb, u16* __restrict__ feb)
{
  __shared__ u16 xs[6*RSTR_];   // 15120 B
  int ct = blockIdx.x % 10, rt = blockIdx.x / 10;
  int b = blockIdx.y;
  int x0 = ct*16, y0 = rt*4;
  int tid = threadIdx.x;
  const float* xb = x + (size_t)b*CH_*L_;

  for (int idx = tid; idx < 64*108; idx += 256) {
    int c = idx / 108, rc = idx - c*108;
    int row = rc / 18, col = rc - row*18;
    int gy = y0 + row - 1, gx = x0 + col - 1;
    float v = (gy>=0 && gy<H_ && gx>=0 && gx<W_) ? xb[(size_t)c*L_ + (size_t)gy*W_ + gx] : 0.f;
    xs[row*RSTR_ + col*CB_ + c] = f2bf(v);
  }
  __syncthreads();

  int wave = tid >> 6, lane = tid & 63;
  int lg = lane >> 4, li = lane & 15;

  floatx4 acc[2][4];
  #pragma unroll
  for (int j = 0; j < 2; ++j)
    #pragma unroll
    for (int pr = 0; pr < 4; ++pr) acc[j][pr] = (floatx4)(0.f);

  #pragma unroll
  for (int tap = 0; tap < 9; ++tap) {
    int ky = tap / 3, kx = tap - ky*3;
    short8b A[2][2];
    #pragma unroll
    for (int j = 0; j < 2; ++j) {
      int ot = wave + j*4;
      const u16* wr = wpk + (((size_t)ot*9 + tap)*16 + li)*64;
      A[j][0] = pack8(*(const short4b*)(wr + lg*4),      *(const short4b*)(wr + 16 + lg*4));
      A[j][1] = pack8(*(const short4b*)(wr + 32 + lg*4), *(const short4b*)(wr + 48 + lg*4));
    }
    #pragma unroll
    for (int pr = 0; pr < 4; ++pr) {
      const u16* bp = xs + (pr+ky)*RSTR_ + (li+kx)*CB_;
      short8b B0 = pack8(*(const short4b*)(bp + lg*4),      *(const short4b*)(bp + 16 + lg*4));
      short8b B1 = pack8(*(const short4b*)(bp + 32 + lg*4), *(const short4b*)(bp + 48 + lg*4));
      acc[0][pr] = mfma32(A[0][0], B0, acc[0][pr]);
      acc[0][pr] = mfma32(A[0][1], B1, acc[0][pr]);
      acc[1][pr] = mfma32(A[1][0], B0, acc[1][pr]);
      acc[1][pr] = mfma32(A[1][1], B1, acc[1][pr]);
    }
  }

  int px = x0 + li;
  if (px < W_) {
    #pragma unroll
    for (int pr = 0; pr < 4; ++pr) {
      int p = (y0+pr)*W_ + px;
      short4b v0, v1;
      #pragma unroll
      for (int r = 0; r < 4; ++r) {
        v0[r] = (short)f2bf(acc[0][pr][r]);
        v1[r] = (short)f2bf(acc[1][pr][r]);
      }
      *(short4b*)(yeb + ((size_t)b*L_+p)*64 + wave*16 + lg*4) = v0;
      *(short4b*)(feb + ((size_t)b*L_+p)*64 + wave*16 + lg*4) = v1;
    }
  }
}

// ---------------- hashing: rot staged in LDS (broadcast reads) ---------------
__global__ __launch_bounds__(256) void hash_kernel(
    const float* __restrict__ xe, const float* __restrict__ rot,
    u16* __restrict__ xnb, int* __restrict__ codes)
{
  __shared__ float rl[NH_*HB_*C_];   // [h][i][f], 32 KB
  int tid = threadIdx.x;
  int b = blockIdx.y;
  for (int idx = tid; idx < NH_*HB_*C_; idx += 256) {
    int f = idx & 15; int hi = idx >> 4; int h = hi >> 7; int i = hi & 127;
    rl[idx] = rot[((size_t)f*NH_ + h)*HB_ + i];
  }
  __syncthreads();
  int t = blockIdx.x * 256 + tid;
  if (t >= L_) return;
  float xr[C_];
  float ss = 0.f;
  #pragma unroll
  for (int f = 0; f < C_; ++f) { xr[f] = xe[((size_t)b*L_ + t)*C_ + f]; ss += xr[f]*xr[f]; }
  float inv = 1.f / fmaxf(sqrtf(ss), 5e-5f);
  u32 w[8];
  #pragma unroll
  for (int q = 0; q < 8; ++q)
    w[q] = (u32)f2bf(xr[2*q]*inv) | ((u32)f2bf(xr[2*q+1]*inv) << 16);
  uint4* d = (uint4*)(xnb + ((size_t)b*L_ + t)*C_);
  d[0] = make_uint4(w[0],w[1],w[2],w[3]);
  d[1] = make_uint4(w[4],w[5],w[6],w[7]);
  #pragma unroll
  for (int h = 0; h < NH_; ++h) {
    float best = -1e30f; int bi = 0;
    #pragma unroll 2
    for (int i = 0; i < HB_; ++i) {
      const float4* rp = (const float4*)(rl + (h*HB_ + i)*C_);
      float4 r0 = rp[0], r1 = rp[1], r2 = rp[2], r3 = rp[3];
      float v = 0.f;
      v += xr[0]*r0.x;  v += xr[1]*r0.y;  v += xr[2]*r0.z;  v += xr[3]*r0.w;
      v += xr[4]*r1.x;  v += xr[5]*r1.y;  v += xr[6]*r1.z;  v += xr[7]*r1.w;
      v += xr[8]*r2.x;  v += xr[9]*r2.y;  v += xr[10]*r2.z; v += xr[11]*r2.w;
      v += xr[12]*r3.x; v += xr[13]*r3.y; v += xr[14]*r3.z; v += xr[15]*r3.w;
      if (v > best) { best = v; bi = i; }
    }
    codes[(size_t)b*M_ + h*L_ + t] = bi + h*HB_;
  }
}

// ---------------- weight prep: fc weights bf16 + conv weights A-frag pack ----
__global__ __launch_bounds__(256) void prep_w_kernel(
    const float* __restrict__ w1, const float* __restrict__ w2,
    const float* __restrict__ wa, const float* __restrict__ wf,
    u16* __restrict__ w1b, u16* __restrict__ w2b, u16* __restrict__ wpk)
{
  int i = blockIdx.x*256 + threadIdx.x;
  if (i < CS_*CH_)  w1b[i] = f2bf(w1[i]);
  if (i < CS_*CS_)  w2b[i] = f2bf(w2[i]);
  if (i < 8*9*16*64) {
    int ot = i / (9*16*64); int r = i - ot*(9*16*64);
    int tap = r / (16*64);  int r2 = r - tap*(16*64);
    int o = r2 >> 6, c = r2 & 63;
    const float* src = (ot < 4) ? wa : wf;
    int og = (ot & 3)*16 + o;
    wpk[i] = f2bf(src[((size_t)og*64 + c)*9 + tap]);
  }
}

// ---------------- per-pixel FC via MFMA ------------------------------------
__global__ __launch_bounds__(256) void fc_mfma_kernel(
    const u16* __restrict__ feb, const u16* __restrict__ w1b, const float* __restrict__ b1,
    const u16* __restrict__ w2b, const float* __restrict__ b2, u16* __restrict__ fc2b)
{
  int wid = blockIdx.x*4 + (threadIdx.x >> 6);
  if (wid >= 2*(L_/16)) return;
  int b = wid / (L_/16);
  int p0 = (wid - b*(L_/16)) * 16;
  int lane = threadIdx.x & 63;
  int lg = lane >> 4, li = lane & 15;

  const u16* fr = feb + ((size_t)b*L_ + p0 + li)*CH_;
  short8b feB[2];
  #pragma unroll
  for (int ks = 0; ks < 2; ++ks)
    feB[ks] = pack8(*(const short4b*)(fr + ks*32 + lg*4),
                    *(const short4b*)(fr + ks*32 + 16 + lg*4));

  short4b hq[9];
  #pragma unroll
  for (int s = 0; s < 9; ++s) {
    const u16* wr = w1b + (size_t)(s*16 + li)*CH_ + lg*4;
    short8b a0 = pack8(*(const short4b*)(wr),      *(const short4b*)(wr + 16));
    short8b a1 = pack8(*(const short4b*)(wr + 32), *(const short4b*)(wr + 48));
    floatx4 acc = mfma32(a0, feB[0], (floatx4)(0.f));
    acc = mfma32(a1, feB[1], acc);
    float4 bb = *(const float4*)(b1 + s*16 + lg*4);
    short4b hv;
    hv[0] = (short)f2bf(fmaxf(acc[0] + bb.x, 0.f));
    hv[1] = (short)f2bf(fmaxf(acc[1] + bb.y, 0.f));
    hv[2] = (short)f2bf(fmaxf(acc[2] + bb.z, 0.f));
    hv[3] = (short)f2bf(fmaxf(acc[3] + bb.w, 0.f));
    hq[s] = hv;
  }
  short4b zero4; zero4[0]=0; zero4[1]=0; zero4[2]=0; zero4[3]=0;
  short8b hB[5];
  #pragma unroll
  for (int ks = 0; ks < 4; ++ks) hB[ks] = pack8(hq[2*ks], hq[2*ks+1]);
  hB[4] = pack8(hq[8], zero4);

  u16* orow = fc2b + ((size_t)b*L_ + p0 + li)*CS_;
  #pragma unroll
  for (int s2 = 0; s2 < 9; ++s2) {
    const u16* wr = w2b + (size_t)(s2*16 + li)*CS_;
    floatx4 acc = (floatx4)(0.f);
    #pragma unroll
    for (int ks = 0; ks < 5; ++ks) {
      short4b lo = *(const short4b*)(wr + ks*32 + lg*4);
      short4b hi = (ks < 4) ? *(const short4b*)(wr + ks*32 + 16 + lg*4) : zero4;
      acc = mfma32(pack8(lo, hi), hB[ks], acc);
    }
    float4 bb = *(const float4*)(b2 + s2*16 + lg*4);
    short4b ov;
    ov[0] = (short)f2bf(acc[0] + bb.x);
    ov[1] = (short)f2bf(acc[1] + bb.y);
    ov[2] = (short)f2bf(acc[2] + bb.z);
    ov[3] = (short)f2bf(acc[3] + bb.w);
    *(short4b*)(orow + s2*16 + lg*4) = ov;
  }
}

// ---------------- stable counting sort: histogram ----------------------------
__global__ __launch_bounds__(256) void hist_kernel(
    const int* __restrict__ codes, int* __restrict__ hist)
{
  __shared__ int lh[NBINS];
  int eb = blockIdx.x, b = blockIdx.y;
  for (int i = threadIdx.x; i < NBINS; i += 256) lh[i] = 0;
  __syncthreads();
  int base = eb * SORT_BLK;
  int end = min(base + SORT_BLK, M_);
  for (int i = base + threadIdx.x; i < end; i += 256)
    atomicAdd(&lh[codes[(size_t)b*M_ + i]], 1);
  __syncthreads();
  for (int i = threadIdx.x; i < NBINS; i += 256)
    hist[((size_t)b*NBLK + eb)*NBINS + i] = lh[i];
}

// ---------------- counting sort: per-bin cross-block prefix ------------------
__global__ __launch_bounds__(NBINS) void prefix_kernel(
    const int* __restrict__ hist, int* __restrict__ blockoff, int* __restrict__ bin_start)
{
  int b = blockIdx.x;
  int c = threadIdx.x;
  int run = 0;
  for (int eb = 0; eb < NBLK; ++eb) {
    size_t idx = ((size_t)b*NBLK + eb)*NBINS + c;
    int v = hist[idx];
    blockoff[idx] = run;
    run += v;
  }
  __shared__ int tot[NBINS];
  tot[c] = run;
  __syncthreads();
  if (c == 0) {
    int s = 0;
    for (int i = 0; i < NBINS; ++i) { int v = tot[i]; tot[i] = s; s += v; }
  }
  __syncthreads();
  bin_start[b*NBINS + c] = tot[c];
}

// ---------------- counting sort: stable in-order scatter ---------------------
__global__ __launch_bounds__(64) void scatter_kernel(
    const int* __restrict__ codes, const int* __restrict__ bin_start,
    const int* __restrict__ blockoff, int* __restrict__ idx_sorted)
{
  __shared__ int off[NBINS];
  __shared__ int lc[SORT_BLK];
  int eb = blockIdx.x, b = blockIdx.y;
  for (int i = threadIdx.x; i < NBINS; i += 64)
    off[i] = bin_start[b*NBINS + i] + blockoff[((size_t)b*NBLK + eb)*NBINS + i];
  int base = eb * SORT_BLK;
  int end = min(base + SORT_BLK, M_);
  for (int i = base + threadIdx.x; i < end; i += 64)
    lc[i - base] = codes[(size_t)b*M_ + i];
  __syncthreads();
  if (threadIdx.x == 0) {
    int n = end - base;
    for (int i = 0; i < n; ++i) {
      int c = lc[i];
      int p = off[c]++;
      idx_sorted[(size_t)b*M_ + p] = base + i;
    }
  }
}

// ---------------- bucket attention: MFMA flash-style, 3 waves ----------------
// Full single V stage (72KB LDS, round-8 structure); bf16 retbuf; setprio(PV);
// per-lane defer-max gate (shfl reduce only on rescale path).
__global__ __launch_bounds__(192) void bucket_kernel(
    const float* __restrict__ xe, const u16* __restrict__ xnb,
    const u16* __restrict__ yeb, const u16* __restrict__ fc2b,
    const int* __restrict__ idx_sorted,
    u16* __restrict__ retbuf, float* __restrict__ bsbuf)
{
  __shared__ u16 k_lds[432*16];        // 13824 B
  __shared__ u16 v_lds[64*436 + 16];   // 55840 B  [ch][key] stride 436
  __shared__ int tj[432];
  __shared__ int o_own[144];

  int flat = blockIdx.x;
  int sid = (flat & 7)*169 + (flat >> 3);
  int k  = sid % K_;
  int hb = sid / K_;
  int h = hb & 3, b = hb >> 2;
  int tid = threadIdx.x;
  int kprev = (k + K_ - 1) % K_, knext = (k + 1) % K_;
  const int* iss = idx_sorted + (size_t)b*M_ + (size_t)h*K_*CS_;
  const u16* xnbb = xnb + (size_t)b*L_*C_;

  for (int j = tid; j < 3*CS_; j += 192) {
    int jb = j / CS_, ji = j - jb*CS_;
    int kj = jb==0 ? k : (jb==1 ? kprev : knext);
    int orig = iss[kj*CS_ + ji];
    int t = orig % L_;
    tj[j] = t;
    if (jb == 0) o_own[ji] = orig;
    const uint4* s = (const uint4*)(xnbb + (size_t)t*C_);
    uint4* d = (uint4*)(k_lds + j*16);
    d[0] = s[0]; d[1] = s[1];
  }
  __syncthreads();

  // stage V^T: pack key-pairs into dwords, [ch][key] layout
  const u16* yb = yeb + (size_t)b*L_*64;
  for (int idx = tid; idx < 216*64; idx += 192) {
    int p2 = idx >> 6, ch = idx & 63;
    u32 lo = yb[(size_t)tj[2*p2]*64 + ch];
    u32 hi = yb[(size_t)tj[2*p2+1]*64 + ch];
    ((u32*)v_lds)[ch*218 + p2] = lo | (hi << 16);
  }

  int wave = tid >> 6, lane = tid & 63;
  int lg = lane >> 4, li = lane & 15;
  int wq0 = wave * 48;

  short4b zero4; zero4[0]=0; zero4[1]=0; zero4[2]=0; zero4[3]=0;

  short8b qb[3];
  const float* xeb_ = xe + (size_t)b*L_*C_;
  #pragma unroll
  for (int n = 0; n < 3; ++n) {
    int t = tj[wq0 + n*16 + li];
    const float* q = xeb_ + (size_t)t*C_ + lg*4;
    short4b v;
    v[0] = (short)f2bf(q[0]); v[1] = (short)f2bf(q[1]);
    v[2] = (short)f2bf(q[2]); v[3] = (short)f2bf(q[3]);
    qb[n] = pack8(v, zero4);
  }

  const u16* fb = fc2b + (size_t)b*L_*CS_;
  u16 bnx[2][3][4];
  #pragma unroll
  for (int s2 = 0; s2 < 2; ++s2)
    #pragma unroll
    for (int r = 0; r < 4; ++r) {
      int t = tj[s2*16 + lg*4 + r];
      #pragma unroll
      for (int n = 0; n < 3; ++n)
        bnx[s2][n][r] = fb[(size_t)t*CS_ + wq0 + n*16 + li];
    }
  __syncthreads();   // v_lds ready

  floatx4 oacc[4][3];
  #pragma unroll
  for (int cg = 0; cg < 4; ++cg)
    #pragma unroll
    for (int n = 0; n < 3; ++n)
      oacc[cg][n] = (floatx4)(0.f);
  float mrun[3] = {-1e30f,-1e30f,-1e30f};
  float lsum[3] = {0.f,0.f,0.f};

  for (int p = 0; p < 13; ++p) {
    int t0 = 2*p, t1 = 2*p+1;
    short8b ak0 = pack8(*(const short4b*)(k_lds + (size_t)(t0*16 + li)*16 + lg*4), zero4);
    short8b ak1 = pack8(*(const short4b*)(k_lds + (size_t)(t1*16 + li)*16 + lg*4), zero4);
    floatx4 s0[3], s1[3];
    #pragma unroll
    for (int n = 0; n < 3; ++n) {
      s0[n] = mfma32(ak0, qb[n], (floatx4)(0.f));
      s1[n] = mfma32(ak1, qb[n], (floatx4)(0.f));
    }
    float bias0[3][4], bias1[3][4];
    #pragma unroll
    for (int n = 0; n < 3; ++n)
      #pragma unroll
      for (int r = 0; r < 4; ++r) {
        bias0[n][r] = bf2f(bnx[0][n][r]);
        bias1[n][r] = bf2f(bnx[1][n][r]);
      }
    if (p < 12) {
      #pragma unroll
      for (int s2 = 0; s2 < 2; ++s2)
        #pragma unroll
        for (int r = 0; r < 4; ++r) {
          int t = tj[(2*p+2+s2)*16 + lg*4 + r];
          #pragma unroll
          for (int n = 0; n < 3; ++n)
            bnx[s2][n][r] = fb[(size_t)t*CS_ + wq0 + n*16 + li];
        }
    } else {
      #pragma unroll
      for (int r = 0; r < 4; ++r) {
        int t = tj[26*16 + lg*4 + r];
        #pragma unroll
        for (int n = 0; n < 3; ++n)
          bnx[0][n][r] = fb[(size_t)t*CS_ + wq0 + n*16 + li];
      }
    }

    short8b pb[3];
    #pragma unroll
    for (int n = 0; n < 3; ++n) {
      float a0[4], a1[4];
      #pragma unroll
      for (int r = 0; r < 4; ++r) { a0[r] = s0[n][r] + bias0[n][r]; a1[r] = s1[n][r] + bias1[n][r]; }
      float lmax = fmaxf(fmaxf(fmaxf(a0[0],a0[1]), fmaxf(a0[2],a0[3])),
                         fmaxf(fmaxf(a1[0],a1[1]), fmaxf(a1[2],a1[3])));
      // per-lane gate; cross-lane reduce only on (rare) rescale path
      if (__any(lmax > mrun[n] + 8.f)) {
        float tmax = fmaxf(lmax, __shfl_xor(lmax, 16));
        tmax = fmaxf(tmax, __shfl_xor(tmax, 32));
        float mn = fmaxf(mrun[n], tmax);
        float sc = __expf(mrun[n] - mn);
        lsum[n] *= sc;
        #pragma unroll
        for (int cg = 0; cg < 4; ++cg) {
          oacc[cg][n][0] *= sc; oacc[cg][n][1] *= sc;
          oacc[cg][n][2] *= sc; oacc[cg][n][3] *= sc;
        }
        mrun[n] = mn;
      }
      float pv0[4], pv1[4];
      float ls = 0.f;
      #pragma unroll
      for (int r = 0; r < 4; ++r) {
        pv0[r] = __expf(a0[r] - mrun[n]);
        pv1[r] = __expf(a1[r] - mrun[n]);
        ls += pv0[r] + pv1[r];
      }
      lsum[n] += ls;
      short4b plo, phi;
      #pragma unroll
      for (int r = 0; r < 4; ++r) {
        plo[r] = (short)f2bf(pv0[r]);
        phi[r] = (short)f2bf(pv1[r]);
      }
      pb[n] = pack8(plo, phi);
    }
    __builtin_amdgcn_s_setprio(1);
    #pragma unroll
    for (int cg = 0; cg < 4; ++cg) {
      const u16* vr = v_lds + (size_t)(cg*16 + li)*436 + p*32 + lg*4;
      short8b av = pack8(*(const short4b*)vr, *(const short4b*)(vr + 16));
      #pragma unroll
      for (int n = 0; n < 3; ++n)
        oacc[cg][n] = mfma32(av, pb[n], oacc[cg][n]);
    }
    __builtin_amdgcn_s_setprio(0);
  }

  // tail: tile 26 (keys 416..431), high halves zeroed
  {
    short8b ak0 = pack8(*(const short4b*)(k_lds + (size_t)(26*16 + li)*16 + lg*4), zero4);
    floatx4 s0[3];
    #pragma unroll
    for (int n = 0; n < 3; ++n)
      s0[n] = mfma32(ak0, qb[n], (floatx4)(0.f));
    short8b pb[3];
    #pragma unroll
    for (int n = 0; n < 3; ++n) {
      float a0[4];
      #pragma unroll
      for (int r = 0; r < 4; ++r) a0[r] = s0[n][r] + bf2f(bnx[0][n][r]);
      float lmax = fmaxf(fmaxf(a0[0],a0[1]), fmaxf(a0[2],a0[3]));
      if (__any(lmax > mrun[n] + 8.f)) {
        float tmax = fmaxf(lmax, __shfl_xor(lmax, 16));
        tmax = fmaxf(tmax, __shfl_xor(tmax, 32));
        float mn = fmaxf(mrun[n], tmax);
        float sc = __expf(mrun[n] - mn);
        lsum[n] *= sc;
        #pragma unroll
        for (int cg = 0; cg < 4; ++cg) {
          oacc[cg][n][0] *= sc; oacc[cg][n][1] *= sc;
          oacc[cg][n][2] *= sc; oacc[cg][n][3] *= sc;
        }
        mrun[n] = mn;
      }
      float ls = 0.f;
      short4b plo;
      #pragma unroll
      for (int r = 0; r < 4; ++r) {
        float pv = __expf(a0[r] - mrun[n]);
        ls += pv;
        plo[r] = (short)f2bf(pv);
      }
      lsum[n] += ls;
      pb[n] = pack8(plo, zero4);
    }
    __builtin_amdgcn_s_setprio(1);
    #pragma unroll
    for (int cg = 0; cg < 4; ++cg) {
      const u16* vr = v_lds + (size_t)(cg*16 + li)*436 + 416 + lg*4;
      short8b av = pack8(*(const short4b*)vr, zero4);
      #pragma unroll
      for (int n = 0; n < 3; ++n)
        oacc[cg][n] = mfma32(av, pb[n], oacc[cg][n]);
    }
    __builtin_amdgcn_s_setprio(0);
  }

  float bs[3], inv[3];
  #pragma unroll
  for (int n = 0; n < 3; ++n) {
    float ls = lsum[n];
    ls += __shfl_xor(ls, 16);
    ls += __shfl_xor(ls, 32);
    inv[n] = 1.f / ls;
    bs[n] = mrun[n] + logf(ls);
  }
  if (lane < 16) {
    #pragma unroll
    for (int n = 0; n < 3; ++n)
      bsbuf[(size_t)b*M_ + o_own[wq0 + n*16 + lane]] = bs[n];
  }
  __syncthreads();                        // all waves done with k/v_lds
  u16* o_lds = v_lds;                     // reuse as [144][72] bf16 (20.7 KB)
  #pragma unroll
  for (int cg = 0; cg < 4; ++cg)
    #pragma unroll
    for (int n = 0; n < 3; ++n) {
      short4b ov;
      #pragma unroll
      for (int r = 0; r < 4; ++r) ov[r] = (short)f2bf(oacc[cg][n][r] * inv[n]);
      *(short4b*)(o_lds + (size_t)(wq0 + n*16 + li)*72 + cg*16 + lg*4) = ov;
    }
  __syncthreads();
  u16* rbb = retbuf + (size_t)b*M_*64;
  for (int rr = tid >> 4; rr < 144; rr += 12) {
    int c4 = (tid & 15)*4;
    short4b v = *(const short4b*)(o_lds + (size_t)rr*72 + c4);
    *(short4b*)(rbb + (size_t)o_own[rr]*64 + c4) = v;
  }
}

// ---------------- combine hash rounds (softmax over NH) + residual -----------
__global__ __launch_bounds__(256) void combine_kernel(
    const u16* __restrict__ retbuf, const float* __restrict__ bsbuf,
    const float* __restrict__ x, float* __restrict__ out)
{
  __shared__ float s[64][65];
  __shared__ float prob[NH_][64];
  int b = blockIdx.y;
  int p0 = blockIdx.x * 64;
  int tid = threadIdx.x;
  if (tid < 64) {
    int p = min(p0 + tid, L_-1);
    float bs0 = bsbuf[(size_t)b*M_ + 0*L_ + p];
    float bs1 = bsbuf[(size_t)b*M_ + 1*L_ + p];
    float bs2 = bsbuf[(size_t)b*M_ + 2*L_ + p];
    float bs3 = bsbuf[(size_t)b*M_ + 3*L_ + p];
    float mx = fmaxf(fmaxf(bs0,bs1), fmaxf(bs2,bs3));
    float e0 = __expf(bs0-mx), e1 = __expf(bs1-mx), e2 = __expf(bs2-mx), e3 = __expf(bs3-mx);
    float inv = 1.f / (e0+e1+e2+e3);
    prob[0][tid] = e0*inv; prob[1][tid] = e1*inv;
    prob[2][tid] = e2*inv; prob[3][tid] = e3*inv;
  }
  __syncthreads();
  for (int i = tid; i < 64*64; i += 256) {
    int pp = i >> 6, c = i & 63;
    int p = min(p0 + pp, L_-1);
    float v = 0.f;
    #pragma unroll
    for (int h = 0; h < NH_; ++h)
      v += bf2f(retbuf[(((size_t)b*NH_ + h)*L_ + p)*CH_ + c]) * prob[h][pp];
    s[c][pp] = v;
  }
  __syncthreads();
  for (int i = tid; i < 64*64; i += 256) {
    int pp = i & 63, cc = i >> 6;
    int p = p0 + pp;
    if (p < L_) {
      size_t gi = ((size_t)b*CH_ + cc)*L_ + p;
      out[gi] = s[cc][pp] + x[gi];
    }
  }
}

extern "C" void kernel_launch(void* const* d_in, const int* in_sizes, int n_in,
                              void* d_out, int out_size, void* d_ws, size_t ws_size,
                              hipStream_t stream) {
  const float* x   = (const float*)d_in[0];
  const float* wm  = (const float*)d_in[1];
  const float* wa  = (const float*)d_in[2];
  const float* wf  = (const float*)d_in[3];
  const float* fw1 = (const float*)d_in[4];
  const float* fb1 = (const float*)d_in[5];
  const float* fw2 = (const float*)d_in[6];
  const float* fb2 = (const float*)d_in[7];
  const float* rot = (const float*)d_in[8];
  float* out = (float*)d_out;

  char* p = (char*)d_ws;
  auto alloc = [&](size_t bytes) { char* r = p; p += (bytes + 255) & ~(size_t)255; return r; };
  float* xe      = (float*)alloc(sizeof(float)*(size_t)N_*L_*C_);
  u16*   xnb     = (u16*)  alloc(sizeof(u16)*(size_t)N_*L_*C_);
  u16*   yeb     = (u16*)  alloc(sizeof(u16)*(size_t)N_*L_*CH_);
  u16*   feb     = (u16*)  alloc(sizeof(u16)*(size_t)N_*L_*CH_);
  u16*   fc2b    = (u16*)  alloc(sizeof(u16)*(size_t)N_*L_*CS_);
  u16*   retbuf  = (u16*)  alloc(sizeof(u16)*(size_t)N_*M_*CH_);
  float* bsbuf   = (float*)alloc(sizeof(float)*(size_t)N_*M_);
  int* codes     = (int*)alloc(sizeof(int)*(size_t)N_*M_);
  int* idx_sorted= (int*)alloc(sizeof(int)*(size_t)N_*M_);
  int* hist      = (int*)alloc(sizeof(int)*(size_t)N_*NBLK*NBINS);
  int* blockoff  = (int*)alloc(sizeof(int)*(size_t)N_*NBLK*NBINS);
  int* bin_start = (int*)alloc(sizeof(int)*(size_t)N_*NBINS);
  u16* w1b       = (u16*)alloc(sizeof(u16)*(size_t)CS_*CH_);
  u16* w2b       = (u16*)alloc(sizeof(u16)*(size_t)CS_*CS_);
  u16* wpk       = (u16*)alloc(sizeof(u16)*(size_t)8*9*16*64);

  // 1a. weight prep (fc bf16 + conv A-frag pack)
  prep_w_kernel<<<dim3((8*9*16*64 + 255)/256), 256, 0, stream>>>(fw1, fw2, wa, wf, w1b, w2b, wpk);
  // 1b. xe conv (f32, scalar-cached weights)
  conv_xe_kernel<<<dim3(10*39, N_), 256, 0, stream>>>(x, wm, xe);
  // 1c. ye/fe conv (MFMA bf16)
  conv_mfma_kernel<<<dim3(10*39, N_), 256, 0, stream>>>(x, wpk, yeb, feb);
  // 2. hash + xnorm(bf16), rot in LDS
  hash_kernel<<<dim3((L_ + 255)/256, N_), 256, 0, stream>>>(xe, rot, xnb, codes);
  // 3. per-pixel FC via MFMA (bf16)
  {
    int tiles = 2*(L_/16);
    fc_mfma_kernel<<<dim3((tiles + 3)/4), 256, 0, stream>>>(feb, w1b, fb1, w2b, fb2, fc2b);
  }
  // 4. stable counting sort
  {
    dim3 g(NBLK, N_);
    hist_kernel<<<g, 256, 0, stream>>>(codes, hist);
    prefix_kernel<<<dim3(N_), NBINS, 0, stream>>>(hist, blockoff, bin_start);
    scatter_kernel<<<g, 64, 0, stream>>>(codes, bin_start, blockoff, idx_sorted);
  }
  // 5. bucket attention (MFMA, bf16 out)
  bucket_kernel<<<dim3(K_*NH_*N_), 192, 0, stream>>>(xe, xnb, yeb, fc2b,
                                                     idx_sorted, retbuf, bsbuf);
  // 6. combine
  combine_kernel<<<dim3((L_ + 63)/64, N_), 256, 0, stream>>>(retbuf, bsbuf, x, out);
}

// Round 11
// 413.593 us; speedup vs baseline: 1.1331x; 1.0221x over previous
//
#include <hip/hip_runtime.h>

typedef unsigned short u16;
typedef unsigned int   u32;

#define N_ 2
#define CH_ 64
#define H_ 156
#define W_ 156
#define L_ (H_*W_)          // 24336
#define C_ 16
#define CS_ 144
#define NH_ 4
#define K_ (L_/CS_)         // 169
#define HB_ 128
#define M_ (NH_*L_)         // 97344
#define NBINS 512
#define SORT_BLK 1024
#define NBLK ((M_+SORT_BLK-1)/SORT_BLK)   // 96
#define TS 16
#define NTX ((W_+TS-1)/TS)  // 10
#define NTY ((H_+TS-1)/TS)  // 10
#define CB_ 70              // LDS channel stride (bf16) -> <=2-way bank alias
#define RSTR_ (18*CB_)      // 1260

__device__ __forceinline__ u16 f2bf(float f) {
  union { float f; u32 u; } v; v.f = f;
  u32 r = (v.u + 0x7fffu + ((v.u >> 16) & 1u)) >> 16;   // RNE
  return (u16)r;
}
__device__ __forceinline__ float bf2f(u16 u) {
  union { u32 u; float f; } v; v.u = ((u32)u) << 16;
  return v.f;
}
// HW pair-converter (RNE, bit-identical to f2bf) — T12 recipe, no builtin
__device__ __forceinline__ u32 cvtpk(float lo, float hi) {
  u32 r;
  asm("v_cvt_pk_bf16_f32 %0, %1, %2" : "=v"(r) : "v"(lo), "v"(hi));
  return r;
}

typedef __attribute__((ext_vector_type(4))) short short4b;
typedef __attribute__((ext_vector_type(8))) short short8b;
typedef __attribute__((ext_vector_type(4))) float floatx4;

__device__ __forceinline__ short4b pk4(float a, float b, float c, float d) {
  union { u32 w[2]; short4b s; } u;
  u.w[0] = cvtpk(a, b);
  u.w[1] = cvtpk(c, d);
  return u.s;
}
__device__ __forceinline__ short8b pack8(short4b lo, short4b hi) {
  short8b r;
  r[0]=lo[0]; r[1]=lo[1]; r[2]=lo[2]; r[3]=lo[3];
  r[4]=hi[0]; r[5]=hi[1]; r[6]=hi[2]; r[7]=hi[3];
  return r;
}

__device__ __forceinline__ floatx4 mfma32(short8b a, short8b b, floatx4 c) {
  return __builtin_amdgcn_mfma_f32_16x16x32_bf16(a, b, c, 0, 0, 0);
}

// ---------------- fused convs: z==0 -> xe (f32), z==1 -> ye/fe (MFMA bf16) ---
// grid (390, N_, 2), block 256. Co-residency overlaps latency-bound xe blocks
// with MFMA-heavy ye/fe blocks.
__global__ __launch_bounds__(256) void conv_fused_kernel(
    const float* __restrict__ x, const float* __restrict__ wm,
    const u16* __restrict__ wpk,
    float* __restrict__ xe, u16* __restrict__ yeb, u16* __restrict__ feb)
{
  __shared__ __align__(16) char smem[15120];
  int ct = blockIdx.x % 10, rt = blockIdx.x / 10;
  int b = blockIdx.y;
  int x0 = ct*16, y0 = rt*4;
  int tid = threadIdx.x;
  const float* xb = x + (size_t)b*CH_*L_;

  if (blockIdx.z == 0) {
    // ---- xe path: f32, scalar-cached weights ----
    float (*xs)[6][18] = (float(*)[6][18])smem;
    int px = tid & 63;
    int col = px & 15, row = px >> 4;
    int og = __builtin_amdgcn_readfirstlane(tid >> 6);
    const float* wg = wm + (size_t)og*4*CH_*9;

    float acc[4] = {0.f, 0.f, 0.f, 0.f};
    for (int c0 = 0; c0 < CH_; c0 += 4) {
      __syncthreads();
      for (int i = tid; i < 4*6*18; i += 256) {
        int cc = i / 108, r = i - cc*108;
        int ly = r / 18, lx = r - ly*18;
        int gy = y0 + ly - 1, gx = x0 + lx - 1;
        float v = (gy>=0 && gy<H_ && gx>=0 && gx<W_) ? xb[(size_t)(c0+cc)*L_ + (size_t)gy*W_ + gx] : 0.f;
        xs[cc][ly][lx] = v;
      }
      __syncthreads();
      #pragma unroll
      for (int cc = 0; cc < 4; ++cc) {
        float in[9];
        #pragma unroll
        for (int ky = 0; ky < 3; ++ky)
          #pragma unroll
          for (int kx = 0; kx < 3; ++kx)
            in[ky*3+kx] = xs[cc][row+ky][col+kx];
        const float* wc = wg + (size_t)(c0+cc)*9;
        #pragma unroll
        for (int oo = 0; oo < 4; ++oo) {
          const float* wo = wc + (size_t)oo*CH_*9;
          #pragma unroll
          for (int t = 0; t < 9; ++t) acc[oo] += in[t]*wo[t];
        }
      }
    }
    int gx = x0 + col, gy = y0 + row;
    if (gx < W_) {
      int p = gy*W_ + gx;
      *(float4*)(xe + ((size_t)b*L_+p)*C_ + og*4) = make_float4(acc[0],acc[1],acc[2],acc[3]);
    }
  } else {
    // ---- ye/fe path: implicit-GEMM MFMA bf16 ----
    u16* xs = (u16*)smem;
    // stage in channel-pairs: one cvtpk + u32 LDS write
    for (int idx = tid; idx < 32*108; idx += 256) {
      int c2 = idx / 108, rc = idx - c2*108;
      int row = rc / 18, col = rc - row*18;
      int gy = y0 + row - 1, gx = x0 + col - 1;
      float v0 = 0.f, v1 = 0.f;
      if (gy>=0 && gy<H_ && gx>=0 && gx<W_) {
        size_t base = (size_t)gy*W_ + gx;
        v0 = xb[(size_t)(2*c2  )*L_ + base];
        v1 = xb[(size_t)(2*c2+1)*L_ + base];
      }
      *(u32*)(xs + row*RSTR_ + col*CB_ + 2*c2) = cvtpk(v0, v1);
    }
    __syncthreads();

    int wave = tid >> 6, lane = tid & 63;
    int lg = lane >> 4, li = lane & 15;

    floatx4 acc[2][4];
    #pragma unroll
    for (int j = 0; j < 2; ++j)
      #pragma unroll
      for (int pr = 0; pr < 4; ++pr) acc[j][pr] = (floatx4)(0.f);

    #pragma unroll
    for (int tap = 0; tap < 9; ++tap) {
      int ky = tap / 3, kx = tap - ky*3;
      short8b A[2][2];
      #pragma unroll
      for (int j = 0; j < 2; ++j) {
        int ot = wave + j*4;
        const u16* wr = wpk + (((size_t)ot*9 + tap)*16 + li)*64;
        A[j][0] = pack8(*(const short4b*)(wr + lg*4),      *(const short4b*)(wr + 16 + lg*4));
        A[j][1] = pack8(*(const short4b*)(wr + 32 + lg*4), *(const short4b*)(wr + 48 + lg*4));
      }
      #pragma unroll
      for (int pr = 0; pr < 4; ++pr) {
        const u16* bp = xs + (pr+ky)*RSTR_ + (li+kx)*CB_;
        short8b B0 = pack8(*(const short4b*)(bp + lg*4),      *(const short4b*)(bp + 16 + lg*4));
        short8b B1 = pack8(*(const short4b*)(bp + 32 + lg*4), *(const short4b*)(bp + 48 + lg*4));
        acc[0][pr] = mfma32(A[0][0], B0, acc[0][pr]);
        acc[0][pr] = mfma32(A[0][1], B1, acc[0][pr]);
        acc[1][pr] = mfma32(A[1][0], B0, acc[1][pr]);
        acc[1][pr] = mfma32(A[1][1], B1, acc[1][pr]);
      }
    }

    int px = x0 + li;
    if (px < W_) {
      #pragma unroll
      for (int pr = 0; pr < 4; ++pr) {
        int p = (y0+pr)*W_ + px;
        short4b v0 = pk4(acc[0][pr][0], acc[0][pr][1], acc[0][pr][2], acc[0][pr][3]);
        short4b v1 = pk4(acc[1][pr][0], acc[1][pr][1], acc[1][pr][2], acc[1][pr][3]);
        *(short4b*)(yeb + ((size_t)b*L_+p)*64 + wave*16 + lg*4) = v0;
        *(short4b*)(feb + ((size_t)b*L_+p)*64 + wave*16 + lg*4) = v1;
      }
    }
  }
}

// ---------------- hashing: rot staged in LDS (broadcast reads) ---------------
__global__ __launch_bounds__(256) void hash_kernel(
    const float* __restrict__ xe, const float* __restrict__ rot,
    u16* __restrict__ xnb, int* __restrict__ codes)
{
  __shared__ float rl[NH_*HB_*C_];   // [h][i][f], 32 KB
  int tid = threadIdx.x;
  int b = blockIdx.y;
  for (int idx = tid; idx < NH_*HB_*C_; idx += 256) {
    int f = idx & 15; int hi = idx >> 4; int h = hi >> 7; int i = hi & 127;
    rl[idx] = rot[((size_t)f*NH_ + h)*HB_ + i];
  }
  __syncthreads();
  int t = blockIdx.x * 256 + tid;
  if (t >= L_) return;
  float xr[C_];
  float ss = 0.f;
  #pragma unroll
  for (int f = 0; f < C_; ++f) { xr[f] = xe[((size_t)b*L_ + t)*C_ + f]; ss += xr[f]*xr[f]; }
  float inv = 1.f / fmaxf(sqrtf(ss), 5e-5f);
  u32 w[8];
  #pragma unroll
  for (int q = 0; q < 8; ++q)
    w[q] = cvtpk(xr[2*q]*inv, xr[2*q+1]*inv);
  uint4* d = (uint4*)(xnb + ((size_t)b*L_ + t)*C_);
  d[0] = make_uint4(w[0],w[1],w[2],w[3]);
  d[1] = make_uint4(w[4],w[5],w[6],w[7]);
  #pragma unroll
  for (int h = 0; h < NH_; ++h) {
    float best = -1e30f; int bi = 0;
    #pragma unroll 2
    for (int i = 0; i < HB_; ++i) {
      const float4* rp = (const float4*)(rl + (h*HB_ + i)*C_);
      float4 r0 = rp[0], r1 = rp[1], r2 = rp[2], r3 = rp[3];
      float v = 0.f;
      v += xr[0]*r0.x;  v += xr[1]*r0.y;  v += xr[2]*r0.z;  v += xr[3]*r0.w;
      v += xr[4]*r1.x;  v += xr[5]*r1.y;  v += xr[6]*r1.z;  v += xr[7]*r1.w;
      v += xr[8]*r2.x;  v += xr[9]*r2.y;  v += xr[10]*r2.z; v += xr[11]*r2.w;
      v += xr[12]*r3.x; v += xr[13]*r3.y; v += xr[14]*r3.z; v += xr[15]*r3.w;
      if (v > best) { best = v; bi = i; }
    }
    codes[(size_t)b*M_ + h*L_ + t] = bi + h*HB_;
  }
}

// ---------------- weight prep: fc weights bf16 + conv weights A-frag pack ----
__global__ __launch_bounds__(256) void prep_w_kernel(
    const float* __restrict__ w1, const float* __restrict__ w2,
    const float* __restrict__ wa, const float* __restrict__ wf,
    u16* __restrict__ w1b, u16* __restrict__ w2b, u16* __restrict__ wpk)
{
  int i = blockIdx.x*256 + threadIdx.x;
  if (i < CS_*CH_)  w1b[i] = f2bf(w1[i]);
  if (i < CS_*CS_)  w2b[i] = f2bf(w2[i]);
  if (i < 8*9*16*64) {
    int ot = i / (9*16*64); int r = i - ot*(9*16*64);
    int tap = r / (16*64);  int r2 = r - tap*(16*64);
    int o = r2 >> 6, c = r2 & 63;
    const float* src = (ot < 4) ? wa : wf;
    int og = (ot & 3)*16 + o;
    wpk[i] = f2bf(src[((size_t)og*64 + c)*9 + tap]);
  }
}

// ---------------- per-pixel FC via MFMA ------------------------------------
__global__ __launch_bounds__(256) void fc_mfma_kernel(
    const u16* __restrict__ feb, const u16* __restrict__ w1b, const float* __restrict__ b1,
    const u16* __restrict__ w2b, const float* __restrict__ b2, u16* __restrict__ fc2b)
{
  int wid = blockIdx.x*4 + (threadIdx.x >> 6);
  if (wid >= 2*(L_/16)) return;
  int b = wid / (L_/16);
  int p0 = (wid - b*(L_/16)) * 16;
  int lane = threadIdx.x & 63;
  int lg = lane >> 4, li = lane & 15;

  const u16* fr = feb + ((size_t)b*L_ + p0 + li)*CH_;
  short8b feB[2];
  #pragma unroll
  for (int ks = 0; ks < 2; ++ks)
    feB[ks] = pack8(*(const short4b*)(fr + ks*32 + lg*4),
                    *(const short4b*)(fr + ks*32 + 16 + lg*4));

  short4b hq[9];
  #pragma unroll
  for (int s = 0; s < 9; ++s) {
    const u16* wr = w1b + (size_t)(s*16 + li)*CH_ + lg*4;
    short8b a0 = pack8(*(const short4b*)(wr),      *(const short4b*)(wr + 16));
    short8b a1 = pack8(*(const short4b*)(wr + 32), *(const short4b*)(wr + 48));
    floatx4 acc = mfma32(a0, feB[0], (floatx4)(0.f));
    acc = mfma32(a1, feB[1], acc);
    float4 bb = *(const float4*)(b1 + s*16 + lg*4);
    hq[s] = pk4(fmaxf(acc[0] + bb.x, 0.f), fmaxf(acc[1] + bb.y, 0.f),
                fmaxf(acc[2] + bb.z, 0.f), fmaxf(acc[3] + bb.w, 0.f));
  }
  short4b zero4; zero4[0]=0; zero4[1]=0; zero4[2]=0; zero4[3]=0;
  short8b hB[5];
  #pragma unroll
  for (int ks = 0; ks < 4; ++ks) hB[ks] = pack8(hq[2*ks], hq[2*ks+1]);
  hB[4] = pack8(hq[8], zero4);

  u16* orow = fc2b + ((size_t)b*L_ + p0 + li)*CS_;
  #pragma unroll
  for (int s2 = 0; s2 < 9; ++s2) {
    const u16* wr = w2b + (size_t)(s2*16 + li)*CS_;
    floatx4 acc = (floatx4)(0.f);
    #pragma unroll
    for (int ks = 0; ks < 5; ++ks) {
      short4b lo = *(const short4b*)(wr + ks*32 + lg*4);
      short4b hi = (ks < 4) ? *(const short4b*)(wr + ks*32 + 16 + lg*4) : zero4;
      acc = mfma32(pack8(lo, hi), hB[ks], acc);
    }
    float4 bb = *(const float4*)(b2 + s2*16 + lg*4);
    *(short4b*)(orow + s2*16 + lg*4) =
      pk4(acc[0] + bb.x, acc[1] + bb.y, acc[2] + bb.z, acc[3] + bb.w);
  }
}

// ---------------- stable counting sort: histogram ----------------------------
__global__ __launch_bounds__(256) void hist_kernel(
    const int* __restrict__ codes, int* __restrict__ hist)
{
  __shared__ int lh[NBINS];
  int eb = blockIdx.x, b = blockIdx.y;
  for (int i = threadIdx.x; i < NBINS; i += 256) lh[i] = 0;
  __syncthreads();
  int base = eb * SORT_BLK;
  int end = min(base + SORT_BLK, M_);
  for (int i = base + threadIdx.x; i < end; i += 256)
    atomicAdd(&lh[codes[(size_t)b*M_ + i]], 1);
  __syncthreads();
  for (int i = threadIdx.x; i < NBINS; i += 256)
    hist[((size_t)b*NBLK + eb)*NBINS + i] = lh[i];
}

// ---------------- counting sort: per-bin cross-block prefix ------------------
__global__ __launch_bounds__(NBINS) void prefix_kernel(
    const int* __restrict__ hist, int* __restrict__ blockoff, int* __restrict__ bin_start)
{
  int b = blockIdx.x;
  int c = threadIdx.x;
  int run = 0;
  for (int eb = 0; eb < NBLK; ++eb) {
    size_t idx = ((size_t)b*NBLK + eb)*NBINS + c;
    int v = hist[idx];
    blockoff[idx] = run;
    run += v;
  }
  __shared__ int tot[NBINS];
  tot[c] = run;
  __syncthreads();
  if (c == 0) {
    int s = 0;
    for (int i = 0; i < NBINS; ++i) { int v = tot[i]; tot[i] = s; s += v; }
  }
  __syncthreads();
  bin_start[b*NBINS + c] = tot[c];
}

// ---------------- counting sort: stable in-order scatter ---------------------
__global__ __launch_bounds__(64) void scatter_kernel(
    const int* __restrict__ codes, const int* __restrict__ bin_start,
    const int* __restrict__ blockoff, int* __restrict__ idx_sorted)
{
  __shared__ int off[NBINS];
  __shared__ int lc[SORT_BLK];
  int eb = blockIdx.x, b = blockIdx.y;
  for (int i = threadIdx.x; i < NBINS; i += 64)
    off[i] = bin_start[b*NBINS + i] + blockoff[((size_t)b*NBLK + eb)*NBINS + i];
  int base = eb * SORT_BLK;
  int end = min(base + SORT_BLK, M_);
  for (int i = base + threadIdx.x; i < end; i += 64)
    lc[i - base] = codes[(size_t)b*M_ + i];
  __syncthreads();
  if (threadIdx.x == 0) {
    int n = end - base;
    for (int i = 0; i < n; ++i) {
      int c = lc[i];
      int p = off[c]++;
      idx_sorted[(size_t)b*M_ + p] = base + i;
    }
  }
}

// ---------------- bucket attention: MFMA flash-style, 3 waves ----------------
__global__ __launch_bounds__(192) void bucket_kernel(
    const float* __restrict__ xe, const u16* __restrict__ xnb,
    const u16* __restrict__ yeb, const u16* __restrict__ fc2b,
    const int* __restrict__ idx_sorted,
    u16* __restrict__ retbuf, float* __restrict__ bsbuf)
{
  __shared__ u16 k_lds[432*16];        // 13824 B
  __shared__ u16 v_lds[64*436 + 16];   // 55840 B  [ch][key] stride 436
  __shared__ int tj[432];
  __shared__ int o_own[144];

  int flat = blockIdx.x;
  int sid = (flat & 7)*169 + (flat >> 3);
  int k  = sid % K_;
  int hb = sid / K_;
  int h = hb & 3, b = hb >> 2;
  int tid = threadIdx.x;
  int kprev = (k + K_ - 1) % K_, knext = (k + 1) % K_;
  const int* iss = idx_sorted + (size_t)b*M_ + (size_t)h*K_*CS_;
  const u16* xnbb = xnb + (size_t)b*L_*C_;

  for (int j = tid; j < 3*CS_; j += 192) {
    int jb = j / CS_, ji = j - jb*CS_;
    int kj = jb==0 ? k : (jb==1 ? kprev : knext);
    int orig = iss[kj*CS_ + ji];
    int t = orig % L_;
    tj[j] = t;
    if (jb == 0) o_own[ji] = orig;
    const uint4* s = (const uint4*)(xnbb + (size_t)t*C_);
    uint4* d = (uint4*)(k_lds + j*16);
    d[0] = s[0]; d[1] = s[1];
  }
  __syncthreads();

  const u16* yb = yeb + (size_t)b*L_*64;
  for (int idx = tid; idx < 216*64; idx += 192) {
    int p2 = idx >> 6, ch = idx & 63;
    u32 lo = yb[(size_t)tj[2*p2]*64 + ch];
    u32 hi = yb[(size_t)tj[2*p2+1]*64 + ch];
    ((u32*)v_lds)[ch*218 + p2] = lo | (hi << 16);
  }

  int wave = tid >> 6, lane = tid & 63;
  int lg = lane >> 4, li = lane & 15;
  int wq0 = wave * 48;

  short4b zero4; zero4[0]=0; zero4[1]=0; zero4[2]=0; zero4[3]=0;

  short8b qb[3];
  const float* xeb_ = xe + (size_t)b*L_*C_;
  #pragma unroll
  for (int n = 0; n < 3; ++n) {
    int t = tj[wq0 + n*16 + li];
    const float* q = xeb_ + (size_t)t*C_ + lg*4;
    qb[n] = pack8(pk4(q[0], q[1], q[2], q[3]), zero4);
  }

  const u16* fb = fc2b + (size_t)b*L_*CS_;
  u16 bnx[2][3][4];
  #pragma unroll
  for (int s2 = 0; s2 < 2; ++s2)
    #pragma unroll
    for (int r = 0; r < 4; ++r) {
      int t = tj[s2*16 + lg*4 + r];
      #pragma unroll
      for (int n = 0; n < 3; ++n)
        bnx[s2][n][r] = fb[(size_t)t*CS_ + wq0 + n*16 + li];
    }
  __syncthreads();   // v_lds ready

  floatx4 oacc[4][3];
  #pragma unroll
  for (int cg = 0; cg < 4; ++cg)
    #pragma unroll
    for (int n = 0; n < 3; ++n)
      oacc[cg][n] = (floatx4)(0.f);
  float mrun[3] = {-1e30f,-1e30f,-1e30f};
  float lsum[3] = {0.f,0.f,0.f};

  for (int p = 0; p < 13; ++p) {
    int t0 = 2*p, t1 = 2*p+1;
    short8b ak0 = pack8(*(const short4b*)(k_lds + (size_t)(t0*16 + li)*16 + lg*4), zero4);
    short8b ak1 = pack8(*(const short4b*)(k_lds + (size_t)(t1*16 + li)*16 + lg*4), zero4);
    floatx4 s0[3], s1[3];
    #pragma unroll
    for (int n = 0; n < 3; ++n) {
      s0[n] = mfma32(ak0, qb[n], (floatx4)(0.f));
      s1[n] = mfma32(ak1, qb[n], (floatx4)(0.f));
    }
    float bias0[3][4], bias1[3][4];
    #pragma unroll
    for (int n = 0; n < 3; ++n)
      #pragma unroll
      for (int r = 0; r < 4; ++r) {
        bias0[n][r] = bf2f(bnx[0][n][r]);
        bias1[n][r] = bf2f(bnx[1][n][r]);
      }
    if (p < 12) {
      #pragma unroll
      for (int s2 = 0; s2 < 2; ++s2)
        #pragma unroll
        for (int r = 0; r < 4; ++r) {
          int t = tj[(2*p+2+s2)*16 + lg*4 + r];
          #pragma unroll
          for (int n = 0; n < 3; ++n)
            bnx[s2][n][r] = fb[(size_t)t*CS_ + wq0 + n*16 + li];
        }
    } else {
      #pragma unroll
      for (int r = 0; r < 4; ++r) {
        int t = tj[26*16 + lg*4 + r];
        #pragma unroll
        for (int n = 0; n < 3; ++n)
          bnx[0][n][r] = fb[(size_t)t*CS_ + wq0 + n*16 + li];
      }
    }

    short8b pb[3];
    #pragma unroll
    for (int n = 0; n < 3; ++n) {
      float a0[4], a1[4];
      #pragma unroll
      for (int r = 0; r < 4; ++r) { a0[r] = s0[n][r] + bias0[n][r]; a1[r] = s1[n][r] + bias1[n][r]; }
      float lmax = fmaxf(fmaxf(fmaxf(a0[0],a0[1]), fmaxf(a0[2],a0[3])),
                         fmaxf(fmaxf(a1[0],a1[1]), fmaxf(a1[2],a1[3])));
      if (__any(lmax > mrun[n] + 8.f)) {
        float tmax = fmaxf(lmax, __shfl_xor(lmax, 16));
        tmax = fmaxf(tmax, __shfl_xor(tmax, 32));
        float mn = fmaxf(mrun[n], tmax);
        float sc = __expf(mrun[n] - mn);
        lsum[n] *= sc;
        #pragma unroll
        for (int cg = 0; cg < 4; ++cg) {
          oacc[cg][n][0] *= sc; oacc[cg][n][1] *= sc;
          oacc[cg][n][2] *= sc; oacc[cg][n][3] *= sc;
        }
        mrun[n] = mn;
      }
      float pv0[4], pv1[4];
      float ls = 0.f;
      #pragma unroll
      for (int r = 0; r < 4; ++r) {
        pv0[r] = __expf(a0[r] - mrun[n]);
        pv1[r] = __expf(a1[r] - mrun[n]);
        ls += pv0[r] + pv1[r];
      }
      lsum[n] += ls;
      pb[n] = pack8(pk4(pv0[0],pv0[1],pv0[2],pv0[3]),
                    pk4(pv1[0],pv1[1],pv1[2],pv1[3]));
    }
    __builtin_amdgcn_s_setprio(1);
    #pragma unroll
    for (int cg = 0; cg < 4; ++cg) {
      const u16* vr = v_lds + (size_t)(cg*16 + li)*436 + p*32 + lg*4;
      short8b av = pack8(*(const short4b*)vr, *(const short4b*)(vr + 16));
      #pragma unroll
      for (int n = 0; n < 3; ++n)
        oacc[cg][n] = mfma32(av, pb[n], oacc[cg][n]);
    }
    __builtin_amdgcn_s_setprio(0);
  }

  // tail: tile 26 (keys 416..431), high halves zeroed
  {
    short8b ak0 = pack8(*(const short4b*)(k_lds + (size_t)(26*16 + li)*16 + lg*4), zero4);
    floatx4 s0[3];
    #pragma unroll
    for (int n = 0; n < 3; ++n)
      s0[n] = mfma32(ak0, qb[n], (floatx4)(0.f));
    short8b pb[3];
    #pragma unroll
    for (int n = 0; n < 3; ++n) {
      float a0[4];
      #pragma unroll
      for (int r = 0; r < 4; ++r) a0[r] = s0[n][r] + bf2f(bnx[0][n][r]);
      float lmax = fmaxf(fmaxf(a0[0],a0[1]), fmaxf(a0[2],a0[3]));
      if (__any(lmax > mrun[n] + 8.f)) {
        float tmax = fmaxf(lmax, __shfl_xor(lmax, 16));
        tmax = fmaxf(tmax, __shfl_xor(tmax, 32));
        float mn = fmaxf(mrun[n], tmax);
        float sc = __expf(mrun[n] - mn);
        lsum[n] *= sc;
        #pragma unroll
        for (int cg = 0; cg < 4; ++cg) {
          oacc[cg][n][0] *= sc; oacc[cg][n][1] *= sc;
          oacc[cg][n][2] *= sc; oacc[cg][n][3] *= sc;
        }
        mrun[n] = mn;
      }
      float pv[4];
      float ls = 0.f;
      #pragma unroll
      for (int r = 0; r < 4; ++r) {
        pv[r] = __expf(a0[r] - mrun[n]);
        ls += pv[r];
      }
      lsum[n] += ls;
      pb[n] = pack8(pk4(pv[0],pv[1],pv[2],pv[3]), zero4);
    }
    __builtin_amdgcn_s_setprio(1);
    #pragma unroll
    for (int cg = 0; cg < 4; ++cg) {
      const u16* vr = v_lds + (size_t)(cg*16 + li)*436 + 416 + lg*4;
      short8b av = pack8(*(const short4b*)vr, zero4);
      #pragma unroll
      for (int n = 0; n < 3; ++n)
        oacc[cg][n] = mfma32(av, pb[n], oacc[cg][n]);
    }
    __builtin_amdgcn_s_setprio(0);
  }

  float bs[3], inv[3];
  #pragma unroll
  for (int n = 0; n < 3; ++n) {
    float ls = lsum[n];
    ls += __shfl_xor(ls, 16);
    ls += __shfl_xor(ls, 32);
    inv[n] = 1.f / ls;
    bs[n] = mrun[n] + logf(ls);
  }
  if (lane < 16) {
    #pragma unroll
    for (int n = 0; n < 3; ++n)
      bsbuf[(size_t)b*M_ + o_own[wq0 + n*16 + lane]] = bs[n];
  }
  __syncthreads();                        // all waves done with k/v_lds
  u16* o_lds = v_lds;                     // reuse as [144][72] bf16 (20.7 KB)
  #pragma unroll
  for (int cg = 0; cg < 4; ++cg)
    #pragma unroll
    for (int n = 0; n < 3; ++n) {
      short4b ov = pk4(oacc[cg][n][0]*inv[n], oacc[cg][n][1]*inv[n],
                       oacc[cg][n][2]*inv[n], oacc[cg][n][3]*inv[n]);
      *(short4b*)(o_lds + (size_t)(wq0 + n*16 + li)*72 + cg*16 + lg*4) = ov;
    }
  __syncthreads();
  u16* rbb = retbuf + (size_t)b*M_*64;
  for (int rr = tid >> 4; rr < 144; rr += 12) {
    int c4 = (tid & 15)*4;
    short4b v = *(const short4b*)(o_lds + (size_t)rr*72 + c4);
    *(short4b*)(rbb + (size_t)o_own[rr]*64 + c4) = v;
  }
}

// ---------------- combine hash rounds (softmax over NH) + residual -----------
__global__ __launch_bounds__(256) void combine_kernel(
    const u16* __restrict__ retbuf, const float* __restrict__ bsbuf,
    const float* __restrict__ x, float* __restrict__ out)
{
  __shared__ float s[64][65];
  __shared__ float prob[NH_][64];
  int b = blockIdx.y;
  int p0 = blockIdx.x * 64;
  int tid = threadIdx.x;
  if (tid < 64) {
    int p = min(p0 + tid, L_-1);
    float bs0 = bsbuf[(size_t)b*M_ + 0*L_ + p];
    float bs1 = bsbuf[(size_t)b*M_ + 1*L_ + p];
    float bs2 = bsbuf[(size_t)b*M_ + 2*L_ + p];
    float bs3 = bsbuf[(size_t)b*M_ + 3*L_ + p];
    float mx = fmaxf(fmaxf(bs0,bs1), fmaxf(bs2,bs3));
    float e0 = __expf(bs0-mx), e1 = __expf(bs1-mx), e2 = __expf(bs2-mx), e3 = __expf(bs3-mx);
    float inv = 1.f / (e0+e1+e2+e3);
    prob[0][tid] = e0*inv; prob[1][tid] = e1*inv;
    prob[2][tid] = e2*inv; prob[3][tid] = e3*inv;
  }
  __syncthreads();
  for (int i = tid; i < 64*64; i += 256) {
    int pp = i >> 6, c = i & 63;
    int p = min(p0 + pp, L_-1);
    float v = 0.f;
    #pragma unroll
    for (int h = 0; h < NH_; ++h)
      v += bf2f(retbuf[(((size_t)b*NH_ + h)*L_ + p)*CH_ + c]) * prob[h][pp];
    s[c][pp] = v;
  }
  __syncthreads();
  for (int i = tid; i < 64*64; i += 256) {
    int pp = i & 63, cc = i >> 6;
    int p = p0 + pp;
    if (p < L_) {
      size_t gi = ((size_t)b*CH_ + cc)*L_ + p;
      out[gi] = s[cc][pp] + x[gi];
    }
  }
}

extern "C" void kernel_launch(void* const* d_in, const int* in_sizes, int n_in,
                              void* d_out, int out_size, void* d_ws, size_t ws_size,
                              hipStream_t stream) {
  const float* x   = (const float*)d_in[0];
  const float* wm  = (const float*)d_in[1];
  const float* wa  = (const float*)d_in[2];
  const float* wf  = (const float*)d_in[3];
  const float* fw1 = (const float*)d_in[4];
  const float* fb1 = (const float*)d_in[5];
  const float* fw2 = (const float*)d_in[6];
  const float* fb2 = (const float*)d_in[7];
  const float* rot = (const float*)d_in[8];
  float* out = (float*)d_out;

  char* p = (char*)d_ws;
  auto alloc = [&](size_t bytes) { char* r = p; p += (bytes + 255) & ~(size_t)255; return r; };
  float* xe      = (float*)alloc(sizeof(float)*(size_t)N_*L_*C_);
  u16*   xnb     = (u16*)  alloc(sizeof(u16)*(size_t)N_*L_*C_);
  u16*   yeb     = (u16*)  alloc(sizeof(u16)*(size_t)N_*L_*CH_);
  u16*   feb     = (u16*)  alloc(sizeof(u16)*(size_t)N_*L_*CH_);
  u16*   fc2b    = (u16*)  alloc(sizeof(u16)*(size_t)N_*L_*CS_);
  u16*   retbuf  = (u16*)  alloc(sizeof(u16)*(size_t)N_*M_*CH_);
  float* bsbuf   = (float*)alloc(sizeof(float)*(size_t)N_*M_);
  int* codes     = (int*)alloc(sizeof(int)*(size_t)N_*M_);
  int* idx_sorted= (int*)alloc(sizeof(int)*(size_t)N_*M_);
  int* hist      = (int*)alloc(sizeof(int)*(size_t)N_*NBLK*NBINS);
  int* blockoff  = (int*)alloc(sizeof(int)*(size_t)N_*NBLK*NBINS);
  int* bin_start = (int*)alloc(sizeof(int)*(size_t)N_*NBINS);
  u16* w1b       = (u16*)alloc(sizeof(u16)*(size_t)CS_*CH_);
  u16* w2b       = (u16*)alloc(sizeof(u16)*(size_t)CS_*CS_);
  u16* wpk       = (u16*)alloc(sizeof(u16)*(size_t)8*9*16*64);

  // 1a. weight prep (fc bf16 + conv A-frag pack)
  prep_w_kernel<<<dim3((8*9*16*64 + 255)/256), 256, 0, stream>>>(fw1, fw2, wa, wf, w1b, w2b, wpk);
  // 1b. fused convs (xe f32 blocks + ye/fe MFMA blocks co-resident)
  conv_fused_kernel<<<dim3(390, N_, 2), 256, 0, stream>>>(x, wm, wpk, xe, yeb, feb);
  // 2. hash + xnorm(bf16), rot in LDS
  hash_kernel<<<dim3((L_ + 255)/256, N_), 256, 0, stream>>>(xe, rot, xnb, codes);
  // 3. per-pixel FC via MFMA (bf16)
  {
    int tiles = 2*(L_/16);
    fc_mfma_kernel<<<dim3((tiles + 3)/4), 256, 0, stream>>>(feb, w1b, fb1, w2b, fb2, fc2b);
  }
  // 4. stable counting sort
  {
    dim3 g(NBLK, N_);
    hist_kernel<<<g, 256, 0, stream>>>(codes, hist);
    prefix_kernel<<<dim3(N_), NBINS, 0, stream>>>(hist, blockoff, bin_start);
    scatter_kernel<<<g, 64, 0, stream>>>(codes, bin_start, blockoff, idx_sorted);
  }
  // 5. bucket attention (MFMA, bf16 out)
  bucket_kernel<<<dim3(K_*NH_*N_), 192, 0, stream>>>(xe, xnb, yeb, fc2b,
                                                     idx_sorted, retbuf, bsbuf);
  // 6. combine
  combine_kernel<<<dim3((L_ + 63)/64, N_), 256, 0, stream>>>(retbuf, bsbuf, x, out);
}

// Round 12
// 398.451 us; speedup vs baseline: 1.1762x; 1.0380x over previous
//
#include <hip/hip_runtime.h>

typedef unsigned short u16;
typedef unsigned int   u32;

#define N_ 2
#define CH_ 64
#define H_ 156
#define W_ 156
#define L_ (H_*W_)          // 24336
#define C_ 16
#define CS_ 144
#define NH_ 4
#define K_ (L_/CS_)         // 169
#define HB_ 128
#define M_ (NH_*L_)         // 97344
#define NBINS 512
#define SORT_BLK 1024
#define NBLK ((M_+SORT_BLK-1)/SORT_BLK)   // 96
#define TS 16
#define NTX ((W_+TS-1)/TS)  // 10
#define NTY ((H_+TS-1)/TS)  // 10
#define CB_ 70              // LDS channel stride (bf16) -> <=2-way bank alias
#define RSTR_ (18*CB_)      // 1260

__device__ __forceinline__ u16 f2bf(float f) {
  union { float f; u32 u; } v; v.f = f;
  u32 r = (v.u + 0x7fffu + ((v.u >> 16) & 1u)) >> 16;   // RNE
  return (u16)r;
}
__device__ __forceinline__ float bf2f(u16 u) {
  union { u32 u; float f; } v; v.u = ((u32)u) << 16;
  return v.f;
}
// HW pair-converter (RNE, bit-identical to f2bf) — T12 recipe, no builtin
__device__ __forceinline__ u32 cvtpk(float lo, float hi) {
  u32 r;
  asm("v_cvt_pk_bf16_f32 %0, %1, %2" : "=v"(r) : "v"(lo), "v"(hi));
  return r;
}

typedef __attribute__((ext_vector_type(4))) short short4b;
typedef __attribute__((ext_vector_type(8))) short short8b;
typedef __attribute__((ext_vector_type(4))) float floatx4;

__device__ __forceinline__ short4b pk4(float a, float b, float c, float d) {
  union { u32 w[2]; short4b s; } u;
  u.w[0] = cvtpk(a, b);
  u.w[1] = cvtpk(c, d);
  return u.s;
}
__device__ __forceinline__ short8b pack8(short4b lo, short4b hi) {
  short8b r;
  r[0]=lo[0]; r[1]=lo[1]; r[2]=lo[2]; r[3]=lo[3];
  r[4]=hi[0]; r[5]=hi[1]; r[6]=hi[2]; r[7]=hi[3];
  return r;
}

__device__ __forceinline__ floatx4 mfma32(short8b a, short8b b, floatx4 c) {
  return __builtin_amdgcn_mfma_f32_16x16x32_bf16(a, b, c, 0, 0, 0);
}

// ---------------- fused convs: z==0 -> xe (f32), z==1 -> ye/fe (MFMA bf16) ---
// z=0: single full-channel stage (1 barrier pair, was 32) -> latency fixed.
__global__ __launch_bounds__(256) void conv_fused_kernel(
    const float* __restrict__ x, const float* __restrict__ wm,
    const u16* __restrict__ wpk,
    float* __restrict__ xe, u16* __restrict__ yeb, u16* __restrict__ feb)
{
  __shared__ __align__(16) char smem[29184];   // max(64*114*4, 15120)
  int ct = blockIdx.x % 10, rt = blockIdx.x / 10;
  int b = blockIdx.y;
  int x0 = ct*16, y0 = rt*4;
  int tid = threadIdx.x;
  const float* xb = x + (size_t)b*CH_*L_;

  if (blockIdx.z == 0) {
    // ---- xe path: f32, all 64 channels staged once, scalar-cached weights --
    float* xs = (float*)smem;            // [64][6][19] (row pad -> spread banks)
    int px = tid & 63;
    int col = px & 15, row = px >> 4;
    int og = __builtin_amdgcn_readfirstlane(tid >> 6);
    const float* wg = wm + (size_t)og*4*CH_*9;

    for (int i = tid; i < 64*108; i += 256) {
      int c = i / 108, rc = i - c*108;
      int ly = rc / 18, lx = rc - ly*18;
      int gy = y0 + ly - 1, gx = x0 + lx - 1;
      float v = (gy>=0 && gy<H_ && gx>=0 && gx<W_) ? xb[(size_t)c*L_ + (size_t)gy*W_ + gx] : 0.f;
      xs[c*114 + ly*19 + lx] = v;
    }
    __syncthreads();

    float acc[4] = {0.f, 0.f, 0.f, 0.f};
    #pragma unroll 4
    for (int c = 0; c < CH_; ++c) {
      float in[9];
      #pragma unroll
      for (int ky = 0; ky < 3; ++ky)
        #pragma unroll
        for (int kx = 0; kx < 3; ++kx)
          in[ky*3+kx] = xs[c*114 + (row+ky)*19 + (col+kx)];
      const float* wc = wg + (size_t)c*9;
      #pragma unroll
      for (int oo = 0; oo < 4; ++oo) {
        const float* wo = wc + (size_t)oo*CH_*9;
        #pragma unroll
        for (int t = 0; t < 9; ++t) acc[oo] += in[t]*wo[t];
      }
    }
    int gx = x0 + col, gy = y0 + row;
    if (gx < W_) {
      int p = gy*W_ + gx;
      *(float4*)(xe + ((size_t)b*L_+p)*C_ + og*4) = make_float4(acc[0],acc[1],acc[2],acc[3]);
    }
  } else {
    // ---- ye/fe path: implicit-GEMM MFMA bf16 ----
    u16* xs = (u16*)smem;
    for (int idx = tid; idx < 32*108; idx += 256) {
      int c2 = idx / 108, rc = idx - c2*108;
      int row = rc / 18, col = rc - row*18;
      int gy = y0 + row - 1, gx = x0 + col - 1;
      float v0 = 0.f, v1 = 0.f;
      if (gy>=0 && gy<H_ && gx>=0 && gx<W_) {
        size_t base = (size_t)gy*W_ + gx;
        v0 = xb[(size_t)(2*c2  )*L_ + base];
        v1 = xb[(size_t)(2*c2+1)*L_ + base];
      }
      *(u32*)(xs + row*RSTR_ + col*CB_ + 2*c2) = cvtpk(v0, v1);
    }
    __syncthreads();

    int wave = tid >> 6, lane = tid & 63;
    int lg = lane >> 4, li = lane & 15;

    floatx4 acc[2][4];
    #pragma unroll
    for (int j = 0; j < 2; ++j)
      #pragma unroll
      for (int pr = 0; pr < 4; ++pr) acc[j][pr] = (floatx4)(0.f);

    #pragma unroll
    for (int tap = 0; tap < 9; ++tap) {
      int ky = tap / 3, kx = tap - ky*3;
      short8b A[2][2];
      #pragma unroll
      for (int j = 0; j < 2; ++j) {
        int ot = wave + j*4;
        const u16* wr = wpk + (((size_t)ot*9 + tap)*16 + li)*64;
        A[j][0] = pack8(*(const short4b*)(wr + lg*4),      *(const short4b*)(wr + 16 + lg*4));
        A[j][1] = pack8(*(const short4b*)(wr + 32 + lg*4), *(const short4b*)(wr + 48 + lg*4));
      }
      #pragma unroll
      for (int pr = 0; pr < 4; ++pr) {
        const u16* bp = xs + (pr+ky)*RSTR_ + (li+kx)*CB_;
        short8b B0 = pack8(*(const short4b*)(bp + lg*4),      *(const short4b*)(bp + 16 + lg*4));
        short8b B1 = pack8(*(const short4b*)(bp + 32 + lg*4), *(const short4b*)(bp + 48 + lg*4));
        acc[0][pr] = mfma32(A[0][0], B0, acc[0][pr]);
        acc[0][pr] = mfma32(A[0][1], B1, acc[0][pr]);
        acc[1][pr] = mfma32(A[1][0], B0, acc[1][pr]);
        acc[1][pr] = mfma32(A[1][1], B1, acc[1][pr]);
      }
    }

    int px = x0 + li;
    if (px < W_) {
      #pragma unroll
      for (int pr = 0; pr < 4; ++pr) {
        int p = (y0+pr)*W_ + px;
        short4b v0 = pk4(acc[0][pr][0], acc[0][pr][1], acc[0][pr][2], acc[0][pr][3]);
        short4b v1 = pk4(acc[1][pr][0], acc[1][pr][1], acc[1][pr][2], acc[1][pr][3]);
        *(short4b*)(yeb + ((size_t)b*L_+p)*64 + wave*16 + lg*4) = v0;
        *(short4b*)(feb + ((size_t)b*L_+p)*64 + wave*16 + lg*4) = v1;
      }
    }
  }
}

// ---------------- hashing: rot staged in LDS (broadcast reads) ---------------
__global__ __launch_bounds__(256) void hash_kernel(
    const float* __restrict__ xe, const float* __restrict__ rot,
    u16* __restrict__ xnb, int* __restrict__ codes)
{
  __shared__ float rl[NH_*HB_*C_];   // [h][i][f], 32 KB
  int tid = threadIdx.x;
  int b = blockIdx.y;
  for (int idx = tid; idx < NH_*HB_*C_; idx += 256) {
    int f = idx & 15; int hi = idx >> 4; int h = hi >> 7; int i = hi & 127;
    rl[idx] = rot[((size_t)f*NH_ + h)*HB_ + i];
  }
  __syncthreads();
  int t = blockIdx.x * 256 + tid;
  if (t >= L_) return;
  float xr[C_];
  float ss = 0.f;
  #pragma unroll
  for (int f = 0; f < C_; ++f) { xr[f] = xe[((size_t)b*L_ + t)*C_ + f]; ss += xr[f]*xr[f]; }
  float inv = 1.f / fmaxf(sqrtf(ss), 5e-5f);
  u32 w[8];
  #pragma unroll
  for (int q = 0; q < 8; ++q)
    w[q] = cvtpk(xr[2*q]*inv, xr[2*q+1]*inv);
  uint4* d = (uint4*)(xnb + ((size_t)b*L_ + t)*C_);
  d[0] = make_uint4(w[0],w[1],w[2],w[3]);
  d[1] = make_uint4(w[4],w[5],w[6],w[7]);
  #pragma unroll
  for (int h = 0; h < NH_; ++h) {
    float best = -1e30f; int bi = 0;
    #pragma unroll 2
    for (int i = 0; i < HB_; ++i) {
      const float4* rp = (const float4*)(rl + (h*HB_ + i)*C_);
      float4 r0 = rp[0], r1 = rp[1], r2 = rp[2], r3 = rp[3];
      float v = 0.f;
      v += xr[0]*r0.x;  v += xr[1]*r0.y;  v += xr[2]*r0.z;  v += xr[3]*r0.w;
      v += xr[4]*r1.x;  v += xr[5]*r1.y;  v += xr[6]*r1.z;  v += xr[7]*r1.w;
      v += xr[8]*r2.x;  v += xr[9]*r2.y;  v += xr[10]*r2.z; v += xr[11]*r2.w;
      v += xr[12]*r3.x; v += xr[13]*r3.y; v += xr[14]*r3.z; v += xr[15]*r3.w;
      if (v > best) { best = v; bi = i; }
    }
    codes[(size_t)b*M_ + h*L_ + t] = bi + h*HB_;
  }
}

// ---------------- weight prep: fc weights bf16 + conv weights A-frag pack ----
__global__ __launch_bounds__(256) void prep_w_kernel(
    const float* __restrict__ w1, const float* __restrict__ w2,
    const float* __restrict__ wa, const float* __restrict__ wf,
    u16* __restrict__ w1b, u16* __restrict__ w2b, u16* __restrict__ wpk)
{
  int i = blockIdx.x*256 + threadIdx.x;
  if (i < CS_*CH_)  w1b[i] = f2bf(w1[i]);
  if (i < CS_*CS_)  w2b[i] = f2bf(w2[i]);
  if (i < 8*9*16*64) {
    int ot = i / (9*16*64); int r = i - ot*(9*16*64);
    int tap = r / (16*64);  int r2 = r - tap*(16*64);
    int o = r2 >> 6, c = r2 & 63;
    const float* src = (ot < 4) ? wa : wf;
    int og = (ot & 3)*16 + o;
    wpk[i] = f2bf(src[((size_t)og*64 + c)*9 + tap]);
  }
}

// ---------------- per-pixel FC via MFMA ------------------------------------
__global__ __launch_bounds__(256) void fc_mfma_kernel(
    const u16* __restrict__ feb, const u16* __restrict__ w1b, const float* __restrict__ b1,
    const u16* __restrict__ w2b, const float* __restrict__ b2, u16* __restrict__ fc2b)
{
  int wid = blockIdx.x*4 + (threadIdx.x >> 6);
  if (wid >= 2*(L_/16)) return;
  int b = wid / (L_/16);
  int p0 = (wid - b*(L_/16)) * 16;
  int lane = threadIdx.x & 63;
  int lg = lane >> 4, li = lane & 15;

  const u16* fr = feb + ((size_t)b*L_ + p0 + li)*CH_;
  short8b feB[2];
  #pragma unroll
  for (int ks = 0; ks < 2; ++ks)
    feB[ks] = pack8(*(const short4b*)(fr + ks*32 + lg*4),
                    *(const short4b*)(fr + ks*32 + 16 + lg*4));

  short4b hq[9];
  #pragma unroll
  for (int s = 0; s < 9; ++s) {
    const u16* wr = w1b + (size_t)(s*16 + li)*CH_ + lg*4;
    short8b a0 = pack8(*(const short4b*)(wr),      *(const short4b*)(wr + 16));
    short8b a1 = pack8(*(const short4b*)(wr + 32), *(const short4b*)(wr + 48));
    floatx4 acc = mfma32(a0, feB[0], (floatx4)(0.f));
    acc = mfma32(a1, feB[1], acc);
    float4 bb = *(const float4*)(b1 + s*16 + lg*4);
    hq[s] = pk4(fmaxf(acc[0] + bb.x, 0.f), fmaxf(acc[1] + bb.y, 0.f),
                fmaxf(acc[2] + bb.z, 0.f), fmaxf(acc[3] + bb.w, 0.f));
  }
  short4b zero4; zero4[0]=0; zero4[1]=0; zero4[2]=0; zero4[3]=0;
  short8b hB[5];
  #pragma unroll
  for (int ks = 0; ks < 4; ++ks) hB[ks] = pack8(hq[2*ks], hq[2*ks+1]);
  hB[4] = pack8(hq[8], zero4);

  u16* orow = fc2b + ((size_t)b*L_ + p0 + li)*CS_;
  #pragma unroll
  for (int s2 = 0; s2 < 9; ++s2) {
    const u16* wr = w2b + (size_t)(s2*16 + li)*CS_;
    floatx4 acc = (floatx4)(0.f);
    #pragma unroll
    for (int ks = 0; ks < 5; ++ks) {
      short4b lo = *(const short4b*)(wr + ks*32 + lg*4);
      short4b hi = (ks < 4) ? *(const short4b*)(wr + ks*32 + 16 + lg*4) : zero4;
      acc = mfma32(pack8(lo, hi), hB[ks], acc);
    }
    float4 bb = *(const float4*)(b2 + s2*16 + lg*4);
    *(short4b*)(orow + s2*16 + lg*4) =
      pk4(acc[0] + bb.x, acc[1] + bb.y, acc[2] + bb.z, acc[3] + bb.w);
  }
}

// ---------------- stable counting sort: histogram ----------------------------
__global__ __launch_bounds__(256) void hist_kernel(
    const int* __restrict__ codes, int* __restrict__ hist)
{
  __shared__ int lh[NBINS];
  int eb = blockIdx.x, b = blockIdx.y;
  for (int i = threadIdx.x; i < NBINS; i += 256) lh[i] = 0;
  __syncthreads();
  int base = eb * SORT_BLK;
  int end = min(base + SORT_BLK, M_);
  for (int i = base + threadIdx.x; i < end; i += 256)
    atomicAdd(&lh[codes[(size_t)b*M_ + i]], 1);
  __syncthreads();
  for (int i = threadIdx.x; i < NBINS; i += 256)
    hist[((size_t)b*NBLK + eb)*NBINS + i] = lh[i];
}

// ---------------- counting sort: per-bin cross-block prefix ------------------
__global__ __launch_bounds__(NBINS) void prefix_kernel(
    const int* __restrict__ hist, int* __restrict__ blockoff, int* __restrict__ bin_start)
{
  int b = blockIdx.x;
  int c = threadIdx.x;
  int run = 0;
  for (int eb = 0; eb < NBLK; ++eb) {
    size_t idx = ((size_t)b*NBLK + eb)*NBINS + c;
    int v = hist[idx];
    blockoff[idx] = run;
    run += v;
  }
  __shared__ int tot[NBINS];
  tot[c] = run;
  __syncthreads();
  if (c == 0) {
    int s = 0;
    for (int i = 0; i < NBINS; ++i) { int v = tot[i]; tot[i] = s; s += v; }
  }
  __syncthreads();
  bin_start[b*NBINS + c] = tot[c];
}

// ---------------- counting sort: stable in-order scatter ---------------------
__global__ __launch_bounds__(64) void scatter_kernel(
    const int* __restrict__ codes, const int* __restrict__ bin_start,
    const int* __restrict__ blockoff, int* __restrict__ idx_sorted)
{
  __shared__ int off[NBINS];
  __shared__ int lc[SORT_BLK];
  int eb = blockIdx.x, b = blockIdx.y;
  for (int i = threadIdx.x; i < NBINS; i += 64)
    off[i] = bin_start[b*NBINS + i] + blockoff[((size_t)b*NBLK + eb)*NBINS + i];
  int base = eb * SORT_BLK;
  int end = min(base + SORT_BLK, M_);
  for (int i = base + threadIdx.x; i < end; i += 64)
    lc[i - base] = codes[(size_t)b*M_ + i];
  __syncthreads();
  if (threadIdx.x == 0) {
    int n = end - base;
    for (int i = 0; i < n; ++i) {
      int c = lc[i];
      int p = off[c]++;
      idx_sorted[(size_t)b*M_ + p] = base + i;
    }
  }
}

// ---------------- bucket attention: MFMA flash-style, 3 waves ----------------
__global__ __launch_bounds__(192) void bucket_kernel(
    const float* __restrict__ xe, const u16* __restrict__ xnb,
    const u16* __restrict__ yeb, const u16* __restrict__ fc2b,
    const int* __restrict__ idx_sorted,
    u16* __restrict__ retbuf, float* __restrict__ bsbuf)
{
  __shared__ u16 k_lds[432*16];        // 13824 B
  __shared__ u16 v_lds[64*436 + 16];   // 55840 B  [ch][key] stride 436
  __shared__ int tj[432];
  __shared__ int o_own[144];

  int flat = blockIdx.x;
  int sid = (flat & 7)*169 + (flat >> 3);
  int k  = sid % K_;
  int hb = sid / K_;
  int h = hb & 3, b = hb >> 2;
  int tid = threadIdx.x;
  int kprev = (k + K_ - 1) % K_, knext = (k + 1) % K_;
  const int* iss = idx_sorted + (size_t)b*M_ + (size_t)h*K_*CS_;
  const u16* xnbb = xnb + (size_t)b*L_*C_;

  for (int j = tid; j < 3*CS_; j += 192) {
    int jb = j / CS_, ji = j - jb*CS_;
    int kj = jb==0 ? k : (jb==1 ? kprev : knext);
    int orig = iss[kj*CS_ + ji];
    int t = orig % L_;
    tj[j] = t;
    if (jb == 0) o_own[ji] = orig;
    const uint4* s = (const uint4*)(xnbb + (size_t)t*C_);
    uint4* d = (uint4*)(k_lds + j*16);
    d[0] = s[0]; d[1] = s[1];
  }
  __syncthreads();

  const u16* yb = yeb + (size_t)b*L_*64;
  for (int idx = tid; idx < 216*64; idx += 192) {
    int p2 = idx >> 6, ch = idx & 63;
    u32 lo = yb[(size_t)tj[2*p2]*64 + ch];
    u32 hi = yb[(size_t)tj[2*p2+1]*64 + ch];
    ((u32*)v_lds)[ch*218 + p2] = lo | (hi << 16);
  }

  int wave = tid >> 6, lane = tid & 63;
  int lg = lane >> 4, li = lane & 15;
  int wq0 = wave * 48;

  short4b zero4; zero4[0]=0; zero4[1]=0; zero4[2]=0; zero4[3]=0;

  short8b qb[3];
  const float* xeb_ = xe + (size_t)b*L_*C_;
  #pragma unroll
  for (int n = 0; n < 3; ++n) {
    int t = tj[wq0 + n*16 + li];
    const float* q = xeb_ + (size_t)t*C_ + lg*4;
    qb[n] = pack8(pk4(q[0], q[1], q[2], q[3]), zero4);
  }

  const u16* fb = fc2b + (size_t)b*L_*CS_;
  u16 bnx[2][3][4];
  #pragma unroll
  for (int s2 = 0; s2 < 2; ++s2)
    #pragma unroll
    for (int r = 0; r < 4; ++r) {
      int t = tj[s2*16 + lg*4 + r];
      #pragma unroll
      for (int n = 0; n < 3; ++n)
        bnx[s2][n][r] = fb[(size_t)t*CS_ + wq0 + n*16 + li];
    }
  __syncthreads();   // v_lds ready

  floatx4 oacc[4][3];
  #pragma unroll
  for (int cg = 0; cg < 4; ++cg)
    #pragma unroll
    for (int n = 0; n < 3; ++n)
      oacc[cg][n] = (floatx4)(0.f);
  float mrun[3] = {-1e30f,-1e30f,-1e30f};
  float lsum[3] = {0.f,0.f,0.f};

  for (int p = 0; p < 13; ++p) {
    int t0 = 2*p, t1 = 2*p+1;
    short8b ak0 = pack8(*(const short4b*)(k_lds + (size_t)(t0*16 + li)*16 + lg*4), zero4);
    short8b ak1 = pack8(*(const short4b*)(k_lds + (size_t)(t1*16 + li)*16 + lg*4), zero4);
    floatx4 s0[3], s1[3];
    #pragma unroll
    for (int n = 0; n < 3; ++n) {
      s0[n] = mfma32(ak0, qb[n], (floatx4)(0.f));
      s1[n] = mfma32(ak1, qb[n], (floatx4)(0.f));
    }
    float bias0[3][4], bias1[3][4];
    #pragma unroll
    for (int n = 0; n < 3; ++n)
      #pragma unroll
      for (int r = 0; r < 4; ++r) {
        bias0[n][r] = bf2f(bnx[0][n][r]);
        bias1[n][r] = bf2f(bnx[1][n][r]);
      }
    if (p < 12) {
      #pragma unroll
      for (int s2 = 0; s2 < 2; ++s2)
        #pragma unroll
        for (int r = 0; r < 4; ++r) {
          int t = tj[(2*p+2+s2)*16 + lg*4 + r];
          #pragma unroll
          for (int n = 0; n < 3; ++n)
            bnx[s2][n][r] = fb[(size_t)t*CS_ + wq0 + n*16 + li];
        }
    } else {
      #pragma unroll
      for (int r = 0; r < 4; ++r) {
        int t = tj[26*16 + lg*4 + r];
        #pragma unroll
        for (int n = 0; n < 3; ++n)
          bnx[0][n][r] = fb[(size_t)t*CS_ + wq0 + n*16 + li];
      }
    }

    short8b pb[3];
    #pragma unroll
    for (int n = 0; n < 3; ++n) {
      float a0[4], a1[4];
      #pragma unroll
      for (int r = 0; r < 4; ++r) { a0[r] = s0[n][r] + bias0[n][r]; a1[r] = s1[n][r] + bias1[n][r]; }
      float lmax = fmaxf(fmaxf(fmaxf(a0[0],a0[1]), fmaxf(a0[2],a0[3])),
                         fmaxf(fmaxf(a1[0],a1[1]), fmaxf(a1[2],a1[3])));
      if (__any(lmax > mrun[n] + 8.f)) {
        float tmax = fmaxf(lmax, __shfl_xor(lmax, 16));
        tmax = fmaxf(tmax, __shfl_xor(tmax, 32));
        float mn = fmaxf(mrun[n], tmax);
        float sc = __expf(mrun[n] - mn);
        lsum[n] *= sc;
        #pragma unroll
        for (int cg = 0; cg < 4; ++cg) {
          oacc[cg][n][0] *= sc; oacc[cg][n][1] *= sc;
          oacc[cg][n][2] *= sc; oacc[cg][n][3] *= sc;
        }
        mrun[n] = mn;
      }
      float pv0[4], pv1[4];
      float ls = 0.f;
      #pragma unroll
      for (int r = 0; r < 4; ++r) {
        pv0[r] = __expf(a0[r] - mrun[n]);
        pv1[r] = __expf(a1[r] - mrun[n]);
        ls += pv0[r] + pv1[r];
      }
      lsum[n] += ls;
      pb[n] = pack8(pk4(pv0[0],pv0[1],pv0[2],pv0[3]),
                    pk4(pv1[0],pv1[1],pv1[2],pv1[3]));
    }
    __builtin_amdgcn_s_setprio(1);
    #pragma unroll
    for (int cg = 0; cg < 4; ++cg) {
      const u16* vr = v_lds + (size_t)(cg*16 + li)*436 + p*32 + lg*4;
      short8b av = pack8(*(const short4b*)vr, *(const short4b*)(vr + 16));
      #pragma unroll
      for (int n = 0; n < 3; ++n)
        oacc[cg][n] = mfma32(av, pb[n], oacc[cg][n]);
    }
    __builtin_amdgcn_s_setprio(0);
  }

  // tail: tile 26 (keys 416..431), high halves zeroed
  {
    short8b ak0 = pack8(*(const short4b*)(k_lds + (size_t)(26*16 + li)*16 + lg*4), zero4);
    floatx4 s0[3];
    #pragma unroll
    for (int n = 0; n < 3; ++n)
      s0[n] = mfma32(ak0, qb[n], (floatx4)(0.f));
    short8b pb[3];
    #pragma unroll
    for (int n = 0; n < 3; ++n) {
      float a0[4];
      #pragma unroll
      for (int r = 0; r < 4; ++r) a0[r] = s0[n][r] + bf2f(bnx[0][n][r]);
      float lmax = fmaxf(fmaxf(a0[0],a0[1]), fmaxf(a0[2],a0[3]));
      if (__any(lmax > mrun[n] + 8.f)) {
        float tmax = fmaxf(lmax, __shfl_xor(lmax, 16));
        tmax = fmaxf(tmax, __shfl_xor(tmax, 32));
        float mn = fmaxf(mrun[n], tmax);
        float sc = __expf(mrun[n] - mn);
        lsum[n] *= sc;
        #pragma unroll
        for (int cg = 0; cg < 4; ++cg) {
          oacc[cg][n][0] *= sc; oacc[cg][n][1] *= sc;
          oacc[cg][n][2] *= sc; oacc[cg][n][3] *= sc;
        }
        mrun[n] = mn;
      }
      float pv[4];
      float ls = 0.f;
      #pragma unroll
      for (int r = 0; r < 4; ++r) {
        pv[r] = __expf(a0[r] - mrun[n]);
        ls += pv[r];
      }
      lsum[n] += ls;
      pb[n] = pack8(pk4(pv[0],pv[1],pv[2],pv[3]), zero4);
    }
    __builtin_amdgcn_s_setprio(1);
    #pragma unroll
    for (int cg = 0; cg < 4; ++cg) {
      const u16* vr = v_lds + (size_t)(cg*16 + li)*436 + 416 + lg*4;
      short8b av = pack8(*(const short4b*)vr, zero4);
      #pragma unroll
      for (int n = 0; n < 3; ++n)
        oacc[cg][n] = mfma32(av, pb[n], oacc[cg][n]);
    }
    __builtin_amdgcn_s_setprio(0);
  }

  float bs[3], inv[3];
  #pragma unroll
  for (int n = 0; n < 3; ++n) {
    float ls = lsum[n];
    ls += __shfl_xor(ls, 16);
    ls += __shfl_xor(ls, 32);
    inv[n] = 1.f / ls;
    bs[n] = mrun[n] + logf(ls);
  }
  if (lane < 16) {
    #pragma unroll
    for (int n = 0; n < 3; ++n)
      bsbuf[(size_t)b*M_ + o_own[wq0 + n*16 + lane]] = bs[n];
  }
  __syncthreads();                        // all waves done with k/v_lds
  u16* o_lds = v_lds;                     // reuse as [144][72] bf16 (20.7 KB)
  #pragma unroll
  for (int cg = 0; cg < 4; ++cg)
    #pragma unroll
    for (int n = 0; n < 3; ++n) {
      short4b ov = pk4(oacc[cg][n][0]*inv[n], oacc[cg][n][1]*inv[n],
                       oacc[cg][n][2]*inv[n], oacc[cg][n][3]*inv[n]);
      *(short4b*)(o_lds + (size_t)(wq0 + n*16 + li)*72 + cg*16 + lg*4) = ov;
    }
  __syncthreads();
  u16* rbb = retbuf + (size_t)b*M_*64;
  for (int rr = tid >> 4; rr < 144; rr += 12) {
    int c4 = (tid & 15)*4;
    short4b v = *(const short4b*)(o_lds + (size_t)rr*72 + c4);
    *(short4b*)(rbb + (size_t)o_own[rr]*64 + c4) = v;
  }
}

// ---------------- combine hash rounds (softmax over NH) + residual -----------
__global__ __launch_bounds__(256) void combine_kernel(
    const u16* __restrict__ retbuf, const float* __restrict__ bsbuf,
    const float* __restrict__ x, float* __restrict__ out)
{
  __shared__ float s[64][65];
  __shared__ float prob[NH_][64];
  int b = blockIdx.y;
  int p0 = blockIdx.x * 64;
  int tid = threadIdx.x;
  if (tid < 64) {
    int p = min(p0 + tid, L_-1);
    float bs0 = bsbuf[(size_t)b*M_ + 0*L_ + p];
    float bs1 = bsbuf[(size_t)b*M_ + 1*L_ + p];
    float bs2 = bsbuf[(size_t)b*M_ + 2*L_ + p];
    float bs3 = bsbuf[(size_t)b*M_ + 3*L_ + p];
    float mx = fmaxf(fmaxf(bs0,bs1), fmaxf(bs2,bs3));
    float e0 = __expf(bs0-mx), e1 = __expf(bs1-mx), e2 = __expf(bs2-mx), e3 = __expf(bs3-mx);
    float inv = 1.f / (e0+e1+e2+e3);
    prob[0][tid] = e0*inv; prob[1][tid] = e1*inv;
    prob[2][tid] = e2*inv; prob[3][tid] = e3*inv;
  }
  __syncthreads();
  for (int i = tid; i < 64*64; i += 256) {
    int pp = i >> 6, c = i & 63;
    int p = min(p0 + pp, L_-1);
    float v = 0.f;
    #pragma unroll
    for (int h = 0; h < NH_; ++h)
      v += bf2f(retbuf[(((size_t)b*NH_ + h)*L_ + p)*CH_ + c]) * prob[h][pp];
    s[c][pp] = v;
  }
  __syncthreads();
  for (int i = tid; i < 64*64; i += 256) {
    int pp = i & 63, cc = i >> 6;
    int p = p0 + pp;
    if (p < L_) {
      size_t gi = ((size_t)b*CH_ + cc)*L_ + p;
      out[gi] = s[cc][pp] + x[gi];
    }
  }
}

extern "C" void kernel_launch(void* const* d_in, const int* in_sizes, int n_in,
                              void* d_out, int out_size, void* d_ws, size_t ws_size,
                              hipStream_t stream) {
  const float* x   = (const float*)d_in[0];
  const float* wm  = (const float*)d_in[1];
  const float* wa  = (const float*)d_in[2];
  const float* wf  = (const float*)d_in[3];
  const float* fw1 = (const float*)d_in[4];
  const float* fb1 = (const float*)d_in[5];
  const float* fw2 = (const float*)d_in[6];
  const float* fb2 = (const float*)d_in[7];
  const float* rot = (const float*)d_in[8];
  float* out = (float*)d_out;

  char* p = (char*)d_ws;
  auto alloc = [&](size_t bytes) { char* r = p; p += (bytes + 255) & ~(size_t)255; return r; };
  float* xe      = (float*)alloc(sizeof(float)*(size_t)N_*L_*C_);
  u16*   xnb     = (u16*)  alloc(sizeof(u16)*(size_t)N_*L_*C_);
  u16*   yeb     = (u16*)  alloc(sizeof(u16)*(size_t)N_*L_*CH_);
  u16*   feb     = (u16*)  alloc(sizeof(u16)*(size_t)N_*L_*CH_);
  u16*   fc2b    = (u16*)  alloc(sizeof(u16)*(size_t)N_*L_*CS_);
  u16*   retbuf  = (u16*)  alloc(sizeof(u16)*(size_t)N_*M_*CH_);
  float* bsbuf   = (float*)alloc(sizeof(float)*(size_t)N_*M_);
  int* codes     = (int*)alloc(sizeof(int)*(size_t)N_*M_);
  int* idx_sorted= (int*)alloc(sizeof(int)*(size_t)N_*M_);
  int* hist      = (int*)alloc(sizeof(int)*(size_t)N_*NBLK*NBINS);
  int* blockoff  = (int*)alloc(sizeof(int)*(size_t)N_*NBLK*NBINS);
  int* bin_start = (int*)alloc(sizeof(int)*(size_t)N_*NBINS);
  u16* w1b       = (u16*)alloc(sizeof(u16)*(size_t)CS_*CH_);
  u16* w2b       = (u16*)alloc(sizeof(u16)*(size_t)CS_*CS_);
  u16* wpk       = (u16*)alloc(sizeof(u16)*(size_t)8*9*16*64);

  // 1a. weight prep (fc bf16 + conv A-frag pack)
  prep_w_kernel<<<dim3((8*9*16*64 + 255)/256), 256, 0, stream>>>(fw1, fw2, wa, wf, w1b, w2b, wpk);
  // 1b. fused convs (xe f32 single-stage + ye/fe MFMA, co-resident)
  conv_fused_kernel<<<dim3(390, N_, 2), 256, 0, stream>>>(x, wm, wpk, xe, yeb, feb);
  // 2. hash + xnorm(bf16), rot in LDS
  hash_kernel<<<dim3((L_ + 255)/256, N_), 256, 0, stream>>>(xe, rot, xnb, codes);
  // 3. per-pixel FC via MFMA (bf16)
  {
    int tiles = 2*(L_/16);
    fc_mfma_kernel<<<dim3((tiles + 3)/4), 256, 0, stream>>>(feb, w1b, fb1, w2b, fb2, fc2b);
  }
  // 4. stable counting sort
  {
    dim3 g(NBLK, N_);
    hist_kernel<<<g, 256, 0, stream>>>(codes, hist);
    prefix_kernel<<<dim3(N_), NBINS, 0, stream>>>(hist, blockoff, bin_start);
    scatter_kernel<<<g, 64, 0, stream>>>(codes, bin_start, blockoff, idx_sorted);
  }
  // 5. bucket attention (MFMA, bf16 out)
  bucket_kernel<<<dim3(K_*NH_*N_), 192, 0, stream>>>(xe, xnb, yeb, fc2b,
                                                     idx_sorted, retbuf, bsbuf);
  // 6. combine
  combine_kernel<<<dim3((L_ + 63)/64, N_), 256, 0, stream>>>(retbuf, bsbuf, x, out);
}